// Round 5
// baseline (277.830 us; speedup 1.0000x reference)
//
#include <hip/hip_runtime.h>
#include <math.h>

#define B_ 4
#define T_ 2048
#define E_ 1024
#define H_ 16
#define D_ 64

typedef __bf16 bf16_t;
typedef bf16_t bf16x8 __attribute__((ext_vector_type(8)));
typedef float  f32x4  __attribute__((ext_vector_type(4)));
typedef float  f32x16 __attribute__((ext_vector_type(16)));
typedef unsigned short u16x4 __attribute__((ext_vector_type(4)));
typedef unsigned int   u32x4 __attribute__((ext_vector_type(4)));

static __device__ __forceinline__ unsigned short f2bf(float f) {
    bf16_t h = (bf16_t)f;
    return __builtin_bit_cast(unsigned short, h);
}
static __device__ __forceinline__ unsigned int pk2(float a, float b) {
    return (unsigned int)f2bf(a) | ((unsigned int)f2bf(b) << 16);
}

// async global->LDS, 16B per lane; lds base wave-uniform + lane*16
#define GLD(gp, lp) __builtin_amdgcn_global_load_lds( \
    (const __attribute__((address_space(1))) unsigned int*)(gp), \
    (__attribute__((address_space(3))) unsigned int*)(lp), 16, 0, 0)

#define BAR() __builtin_amdgcn_s_barrier()
#define WAIT_LGKM0() asm volatile("s_waitcnt lgkmcnt(0)" ::: "memory")

// ---------------------------------------------------------------------------
// x fp32 -> bf16
// ---------------------------------------------------------------------------
__global__ void cast_x_kernel(const float* __restrict__ in, unsigned short* __restrict__ out, int n4) {
    int i = blockIdx.x * blockDim.x + threadIdx.x;
    if (i >= n4) return;
    float4 v = ((const float4*)in)[i];
    ushort4 o;
    o.x = f2bf(v.x); o.y = f2bf(v.y); o.z = f2bf(v.z); o.w = f2bf(v.w);
    ((ushort4*)out)[i] = o;
}

// ---------------------------------------------------------------------------
// fused transpose-cast for all 4 weights. grid (16, 64), block 256.
// grp 0..2: Wq/Wk/Wv [h][e][d] -> wf[(grp*1024+h*64+d)][e]; grp 3: Wp [e][n] -> wpt[n][e]
// ---------------------------------------------------------------------------
__global__ void tcast_all(const float* __restrict__ Wq, const float* __restrict__ Wk,
                          const float* __restrict__ Wv, const float* __restrict__ Wp,
                          unsigned short* __restrict__ wf, unsigned short* __restrict__ wpt) {
    __shared__ unsigned short Ts[64 * 66];
    const int grp = blockIdx.y >> 4, yy = blockIdx.y & 15;
    const float* in; unsigned short* out; int yA, S;
    if (grp == 3) { in = Wp; out = wpt; yA = 64;    S = 1024; }
    else {
        in = (grp == 0) ? Wq : (grp == 1) ? Wk : Wv;
        out = wf + (size_t)grp * 1024 * 1024; yA = 65536; S = 64;
    }
    const int tid = threadIdx.x;
    const int r = tid >> 2, c4 = tid & 3;
    const float* ip = in + (size_t)yA * yy + (size_t)(blockIdx.x * 64 + r) * S + c4 * 16;
    #pragma unroll
    for (int j = 0; j < 4; ++j) {
        float4 v = *(const float4*)&ip[j * 4];
        Ts[(c4 * 16 + j * 4 + 0) * 66 + r] = f2bf(v.x);
        Ts[(c4 * 16 + j * 4 + 1) * 66 + r] = f2bf(v.y);
        Ts[(c4 * 16 + j * 4 + 2) * 66 + r] = f2bf(v.z);
        Ts[(c4 * 16 + j * 4 + 3) * 66 + r] = f2bf(v.w);
    }
    __syncthreads();
    unsigned short* op = out + (size_t)(yy * 64 + r) * 1024 + blockIdx.x * 64 + c4 * 16;
    #pragma unroll
    for (int j = 0; j < 4; ++j) {
        u16x4 pk;
        #pragma unroll
        for (int m = 0; m < 4; ++m) pk[m] = Ts[r * 66 + c4 * 16 + j * 4 + m];
        *(u16x4*)&op[j * 4] = pk;
    }
}

// ---------------------------------------------------------------------------
// Fused QKV GEMM: [8192 x 1024] x [3072 x 1024]^T.
// 256x256 tile, 512 threads (8 waves 2Mx4N), 8-phase schedule, BK=64,
// 1 half-tile (2 GLD) staged per phase, vmcnt(4) at P4/P8 only, 128KB LDS
// double-buffer, T2 swizzle via pre-swizzled global source (rule 21).
// STAGING LEDGER (verified race-free, round 4):
//   P1:A0(t1) P2:A1(t1) P3:B0(t0+2) P4:B1(t0+2)+vmcnt(4)
//   P5:A0(t0+2) P6:A1(t0+2) P7:B0(t1+2) P8:B1(t1+2)+vmcnt(4)
// q scaled 0.125 (+bias); k +bias; v (+bias) stored transposed [bh][64][T].
// grid (32, 12), block 512.
// ---------------------------------------------------------------------------
__global__ __launch_bounds__(512, 2) void qkv_gemm(
    const unsigned short* __restrict__ xb,
    const unsigned short* __restrict__ wf,
    const float* __restrict__ bq, const float* __restrict__ bk, const float* __restrict__ bv,
    unsigned short* __restrict__ qo, unsigned short* __restrict__ ko,
    unsigned short* __restrict__ vt)
{
    // buf q at sm + q*32768 (u16): A0 @0, A1 @8192, B0 @16384, B1 @24576
    __shared__ __align__(16) unsigned short sm[65536];   // 128 KiB

    const int tid = threadIdx.x;
    const int w = tid >> 6, lane = tid & 63;
    const int wr = w >> 2, wc = w & 3;                  // wave -> (Mhalf, Nquarter)
    const int l15 = lane & 15, quad = lane >> 4, lsw = l15 & 7;
    const int m0 = blockIdx.x * 256;
    const int n0 = blockIdx.y * 256;

    f32x4 acc[8][4];
    #pragma unroll
    for (int i = 0; i < 8; ++i)
        #pragma unroll
        for (int j = 0; j < 4; ++j) acc[i][j] = (f32x4){0.f, 0.f, 0.f, 0.f};

    // T2: linear GLD dest + inverse-swizzled global source (rule 21).
    const int swzE = (((lane & 7) ^ (lane >> 3)) * 8);
    const unsigned short* Agb = xb + (size_t)(m0 + w * 16 + (lane >> 3)) * 1024 + swzE;
    const unsigned short* Bgb = wf + (size_t)(n0 + w * 16 + (lane >> 3)) * 1024 + swzE;

    // stage one half-tile (2 GLD/thread): which 0=A0 1=A1 2=B0 3=B1, tile t
    auto stage_half = [&](int t, int which) {
        unsigned short* dst = sm + (t & 1) * 32768 + which * 8192 + w * 1024;
        const unsigned short* src = ((which < 2) ? Agb : Bgb)
                                  + (size_t)((which & 1) * 128) * 1024 + t * 64;
        GLD(src, dst);
        GLD(src + (size_t)8 * 1024, dst + 512);
    };
    // swizzled fragment reads: slot c of row r lives at slot c^(r&7); r&7==l15&7
    auto rdA = [&](int t, int fm, int ks) {
        const int row = wr * 128 + fm * 16 + l15;
        return *(const bf16x8*)&sm[(t & 1) * 32768 + (row >> 7) * 8192
                                   + (row & 127) * 64 + (((ks * 4 + quad) ^ lsw) * 8)];
    };
    auto rdB = [&](int t, int fn, int ks) {
        const int row = wc * 64 + fn * 16 + l15;
        return *(const bf16x8*)&sm[(t & 1) * 32768 + 16384 + (row >> 7) * 8192
                                   + (row & 127) * 64 + (((ks * 4 + quad) ^ lsw) * 8)];
    };

    // prologue: tile0 all 4 halves + tile1 {B0,B1}; A0/A1(t1) staged at P1/P2.
    stage_half(0, 0); stage_half(0, 1); stage_half(0, 2); stage_half(0, 3);
    stage_half(1, 2); stage_half(1, 3);
    asm volatile("s_waitcnt vmcnt(4)" ::: "memory");
    BAR();

    #define MFMA_Q(mb, nb) \
        __builtin_amdgcn_s_setprio(1); \
        _Pragma("unroll") \
        for (int i_ = 0; i_ < 4; ++i_) \
            _Pragma("unroll") \
            for (int j_ = 0; j_ < 2; ++j_) \
                _Pragma("unroll") \
                for (int ks_ = 0; ks_ < 2; ++ks_) \
                    acc[(mb) + i_][(nb) + j_] = __builtin_amdgcn_mfma_f32_16x16x32_bf16( \
                        fA[i_][ks_], fB[(nb) + j_][ks_], acc[(mb) + i_][(nb) + j_], 0, 0, 0); \
        __builtin_amdgcn_s_setprio(0);

    #pragma unroll 1
    for (int it = 0; it < 8; ++it) {
        const int t0 = 2 * it, t1 = 2 * it + 1;
        const bool more = it < 7;
        bf16x8 fA[4][2], fB[4][2];

        // ---- P1: reads fm0-3 + fn0-1 of t0 (12); stage A0(t1)
        #pragma unroll
        for (int m = 0; m < 4; ++m) { fA[m][0] = rdA(t0, m, 0); fA[m][1] = rdA(t0, m, 1); }
        #pragma unroll
        for (int n = 0; n < 2; ++n) { fB[n][0] = rdB(t0, n, 0); fB[n][1] = rdB(t0, n, 1); }
        stage_half(t1, 0);
        BAR(); WAIT_LGKM0();
        MFMA_Q(0, 0);
        BAR();

        // ---- P2: reads fn2-3 of t0 (4); stage A1(t1)
        #pragma unroll
        for (int n = 0; n < 2; ++n) { fB[2 + n][0] = rdB(t0, 2 + n, 0); fB[2 + n][1] = rdB(t0, 2 + n, 1); }
        stage_half(t1, 1);
        BAR(); WAIT_LGKM0();
        MFMA_Q(0, 2);
        BAR();

        // ---- P3: reads fm4-7 of t0 (8); stage B0(t0+2)  [B(t0) last read P2]
        #pragma unroll
        for (int m = 0; m < 4; ++m) { fA[m][0] = rdA(t0, 4 + m, 0); fA[m][1] = rdA(t0, 4 + m, 1); }
        if (more) stage_half(t0 + 2, 2);
        BAR(); WAIT_LGKM0();
        MFMA_Q(4, 2);
        BAR();

        // ---- P4: no reads; stage B1(t0+2); vmcnt(4) -> t1 fully landed
        if (more) {
            stage_half(t0 + 2, 3);
            asm volatile("s_waitcnt vmcnt(4)" ::: "memory");
        } else {
            asm volatile("s_waitcnt vmcnt(0)" ::: "memory");
        }
        BAR();
        MFMA_Q(4, 0);
        BAR();

        // ---- P5: reads fm0-3 + fn0-1 of t1 (12); stage A0(t0+2)  [A(t0) last read P3]
        #pragma unroll
        for (int m = 0; m < 4; ++m) { fA[m][0] = rdA(t1, m, 0); fA[m][1] = rdA(t1, m, 1); }
        #pragma unroll
        for (int n = 0; n < 2; ++n) { fB[n][0] = rdB(t1, n, 0); fB[n][1] = rdB(t1, n, 1); }
        if (more) stage_half(t0 + 2, 0);
        BAR(); WAIT_LGKM0();
        MFMA_Q(0, 0);
        BAR();

        // ---- P6: reads fn2-3 of t1 (4); stage A1(t0+2)
        #pragma unroll
        for (int n = 0; n < 2; ++n) { fB[2 + n][0] = rdB(t1, 2 + n, 0); fB[2 + n][1] = rdB(t1, 2 + n, 1); }
        if (more) stage_half(t0 + 2, 1);
        BAR(); WAIT_LGKM0();
        MFMA_Q(0, 2);
        BAR();

        // ---- P7: reads fm4-7 of t1 (8); stage B0(t1+2)  [B(t1) last read P6]
        #pragma unroll
        for (int m = 0; m < 4; ++m) { fA[m][0] = rdA(t1, 4 + m, 0); fA[m][1] = rdA(t1, 4 + m, 1); }
        if (more) stage_half(t1 + 2, 2);
        BAR(); WAIT_LGKM0();
        MFMA_Q(4, 2);
        BAR();

        // ---- P8: no reads; stage B1(t1+2); vmcnt(4) -> t0+2 fully landed
        if (more) {
            stage_half(t1 + 2, 3);
            asm volatile("s_waitcnt vmcnt(4)" ::: "memory");
        } else {
            asm volatile("s_waitcnt vmcnt(0)" ::: "memory");
        }
        BAR();
        MFMA_Q(4, 0);
        BAR();
    }
    #undef MFMA_Q

    const int which = n0 >> 10;           // 256-wide N-tile lies in one of q/k/v
    const int nb = n0 & 1023;
    if (which < 2) {
        const float* bias = which ? bk : bq;
        unsigned short* outp = which ? ko : qo;
        const float sc = which ? 1.f : 0.125f;
        #pragma unroll
        for (int fm = 0; fm < 8; ++fm)
            #pragma unroll
            for (int fn = 0; fn < 4; ++fn) {
                int colg = nb + wc * 64 + fn * 16 + l15;
                int h = colg >> 6, d = colg & 63;
                float bi = bias[colg];
                #pragma unroll
                for (int r = 0; r < 4; ++r) {
                    int row = m0 + wr * 128 + fm * 16 + quad * 4 + r;
                    int b = row >> 11, t = row & 2047;
                    outp[(((size_t)b * 16 + h) * 2048 + t) * 64 + d] = f2bf((acc[fm][fn][r] + bi) * sc);
                }
            }
    } else {
        // V: transpose via LDS, 4 sub-blocks of 128(m) x 128(n), padded stride 136
        const int b = m0 >> 11;
        for (int mh = 0; mh < 2; ++mh)
            for (int nh = 0; nh < 2; ++nh) {
                __syncthreads();
                if (wr == mh && (wc >> 1) == nh) {
                    const int cc = wc & 1;
                    #pragma unroll
                    for (int fm = 0; fm < 8; ++fm)
                        #pragma unroll
                        for (int fn = 0; fn < 4; ++fn) {
                            int colL = cc * 64 + fn * 16 + l15;          // 0..127
                            int colg = nb + nh * 128 + colL;
                            float bi = bv[colg];
                            u16x4 pk;
                            #pragma unroll
                            for (int r = 0; r < 4; ++r) pk[r] = f2bf(acc[fm][fn][r] + bi);
                            *(u16x4*)&sm[colL * 136 + fm * 16 + quad * 4] = pk;
                        }
                }
                __syncthreads();
                const int nl = tid >> 2, tq = tid & 3;                   // col 0..127, quarter
                const int colg = nb + nh * 128 + nl;
                const int h = colg >> 6, d = colg & 63;
                const int t0 = (m0 & 2047) + mh * 128;
                unsigned short* dst = vt + (((size_t)b * 16 + h) * 64 + d) * 2048 + t0 + tq * 32;
                #pragma unroll
                for (int j = 0; j < 4; ++j)
                    *(float4*)&dst[j * 8] = *(const float4*)&sm[nl * 136 + tq * 32 + j * 8];
            }
    }
}

// ---------------------------------------------------------------------------
// Flash attention v2: key-split wave pairs for 4 waves/SIMD occupancy.
// q pre-scaled 1/8 [bh][t][64]; k [bh][t][64]; v transposed [bh][64][T].
// Block: 256 thr = 4 waves; 64 queries/block (2 q-halves x 2 key-halves).
// Wave (qhalf, ksel): queries qt*64+qhalf*32..+31, keys ksel*32..+31 of each
// 64-key tile. No-max softmax is LINEAR => partial O/lsum just add at leg end
// (combine via freed K/V LDS). P kept fully in-register: swapped QK^T makes
// the key axis lane-local; only the h<->h+32 exchange is cross-lane
// (__shfl_xor 32 + selects; derivation verified vs old Ps layout).
// Legs pair q-tiles (p, 31-p) => every block exactly 33 trips.
// grid (64 bh, 16 pairs), block 256. LDS 16.5KB -> 4 blocks/CU.
// C/D layout (verified): col=lane&31, row=(reg&3)+8*(reg>>2)+4*(lane>>5).
// ---------------------------------------------------------------------------
__global__ __launch_bounds__(256, 4) void attn_kernel(
    const unsigned short* __restrict__ q, const unsigned short* __restrict__ k,
    const unsigned short* __restrict__ vt, unsigned short* __restrict__ att2)
{
    __shared__ __align__(16) unsigned short Ks[64 * 64];   // doubles as Ob[qhalf=0]
    __shared__ __align__(16) unsigned short Vs[64 * 64];   // doubles as Ob[qhalf=1]
    __shared__ float Ls[2][64];

    const int tid = threadIdx.x;
    const int w = tid >> 6, lane = tid & 63;
    const int l31 = lane & 31, h = lane >> 5;
    const int qhalf = w >> 1, ksel = w & 1;
    const int bh = blockIdx.x;

    const unsigned short* kb = k  + (size_t)bh * 2048 * 64;
    const unsigned short* vb = vt + (size_t)bh * 64 * 2048;
    const int sr = tid >> 2;          // staging row 0..63
    const int sc0 = tid & 3;          // staging chunk 0..3 (+4)
    const int ssw = sr & 7;

    for (int leg = 0; leg < 2; ++leg) {
        const int qt = leg ? (31 - (int)blockIdx.y) : (int)blockIdx.y;
        const int qb0 = qt * 64;
        const int qmin = qb0 + qhalf * 32;     // wave's first query
        const int qg = qmin + l31;             // query owned as S^T COLUMN
        const int trips = qt + 1;

        // Q B-fragments straight from global: B[k=d][n=query]
        bf16x8 fQ[4];
        {
            const unsigned short* qp = q + ((size_t)bh * 2048 + qg) * 64 + h * 8;
            #pragma unroll
            for (int ks = 0; ks < 4; ++ks) fQ[ks] = *(const bf16x8*)&qp[ks * 16];
        }

        f32x16 O[2];
        #pragma unroll
        for (int nt = 0; nt < 2; ++nt)
            #pragma unroll
            for (int i = 0; i < 16; ++i) O[nt][i] = 0.f;
        float lsum = 0.f;

        for (int jt = 0; jt < trips; ++jt) {
            __syncthreads();
            {   // stage K (rows=key, cols=d) and V^T (rows=d, cols=key), swizzled chunks
                const unsigned short* kg = kb + (size_t)(jt * 64) * 64;
                const unsigned short* vg = vb + jt * 64;
                #pragma unroll
                for (int it = 0; it < 2; ++it) {
                    int ci = sc0 + 4 * it;
                    int sw = ((ci ^ ssw)) * 8;
                    *(float4*)&Ks[sr * 64 + sw] = *(const float4*)&kg[(size_t)sr * 64 + ci * 8];
                    *(float4*)&Vs[sr * 64 + sw] = *(const float4*)&vg[(size_t)sr * 2048 + ci * 8];
                }
            }
            __syncthreads();

            const int wk0 = jt * 64 + ksel * 32;    // wave's 32-key base
            if (wk0 <= qmin + 31) {                 // wave-uniform skip
                // S^T = K(32 rows) . Q^T : 4 MFMA over d
                f32x16 S;
                #pragma unroll
                for (int i = 0; i < 16; ++i) S[i] = 0.f;
                __builtin_amdgcn_s_setprio(1);
                {
                    const int row = ksel * 32 + l31, rs = l31 & 7;
                    #pragma unroll
                    for (int ks = 0; ks < 4; ++ks) {
                        bf16x8 aK = *(const bf16x8*)&Ks[row * 64 + ((2 * ks + h) ^ rs) * 8];
                        S = __builtin_amdgcn_mfma_f32_32x32x16_bf16(aK, fQ[ks], S, 0, 0, 0);
                    }
                }
                __builtin_amdgcn_s_setprio(0);

                // element (4g+r): key = wk0 + 8g + 4h + r, query col = qg.
                const bool need_mask = (wk0 + 31) > qmin;
                unsigned int e0[4], e1[4];
                #pragma unroll
                for (int g = 0; g < 4; ++g) {
                    float p[4];
                    #pragma unroll
                    for (int r = 0; r < 4; ++r) {
                        float pv = __expf(S[4 * g + r]);
                        if (need_mask) {
                            int key = wk0 + 8 * g + 4 * h + r;
                            if (key > qg) pv = 0.f;
                        }
                        p[r] = pv;
                        lsum += pv;
                    }
                    e0[g] = pk2(p[0], p[1]);
                    e1[g] = pk2(p[2], p[3]);
                }

                // build A-fragments in-register via half-wave exchange.
                // lane (l31,h) group g holds key offsets 8g+4h+{0..3}; fragment
                // for slice s needs keys s*16+8h+{0..7} = groups {2s,2s+1}.
                bf16x8 aP[2];
                #pragma unroll
                for (int s = 0; s < 2; ++s) {
                    const int ge = 2 * s, go = 2 * s + 1;
                    unsigned int own0 = h ? e0[go] : e0[ge];
                    unsigned int snd0 = h ? e0[ge] : e0[go];
                    unsigned int rcv0 = (unsigned int)__shfl_xor((int)snd0, 32);
                    unsigned int own1 = h ? e1[go] : e1[ge];
                    unsigned int snd1 = h ? e1[ge] : e1[go];
                    unsigned int rcv1 = (unsigned int)__shfl_xor((int)snd1, 32);
                    u32x4 t;
                    t[0] = h ? rcv0 : own0;   // keys +0,+1
                    t[1] = h ? rcv1 : own1;   // keys +2,+3
                    t[2] = h ? own0 : rcv0;   // keys +4,+5
                    t[3] = h ? own1 : rcv1;   // keys +6,+7
                    aP[s] = __builtin_bit_cast(bf16x8, t);
                }

                // O += P.V over this wave's 32 keys (slices ks2 = 2*ksel+s)
                __builtin_amdgcn_s_setprio(1);
                #pragma unroll
                for (int s = 0; s < 2; ++s) {
                    const int ks2 = 2 * ksel + s;
                    #pragma unroll
                    for (int nt = 0; nt < 2; ++nt) {
                        const int drow = nt * 32 + l31;
                        bf16x8 bV = *(const bf16x8*)&Vs[drow * 64 + ((2 * ks2 + h) ^ (drow & 7)) * 8];
                        O[nt] = __builtin_amdgcn_mfma_f32_32x32x16_bf16(aP[s], bV, O[nt], 0, 0, 0);
                    }
                }
                __builtin_amdgcn_s_setprio(0);
            }
        }

        // merge h-halves of lsum (query qg lives in lanes l31 and l31+32)
        lsum += __shfl_xor(lsum, 32);

        // pair combine: ksel=1 publishes partial O/lsum via freed K/V LDS
        __syncthreads();
        float* ObH = (float*)(qhalf ? (void*)Vs : (void*)Ks);
        if (ksel) {
            #pragma unroll
            for (int nt = 0; nt < 2; ++nt)
                #pragma unroll
                for (int i = 0; i < 16; ++i)
                    ObH[(nt * 16 + i) * 64 + lane] = O[nt][i];
            if (lane < 32) Ls[qhalf][l31] = lsum;
        }
        __syncthreads();
        if (!ksel) {
            #pragma unroll
            for (int nt = 0; nt < 2; ++nt)
                #pragma unroll
                for (int i = 0; i < 16; ++i)
                    O[nt][i] += ObH[(nt * 16 + i) * 64 + lane];
            const float inv = 1.f / (lsum + Ls[qhalf][l31]);

            // O[nt][4g+r]: query row 8g+4h+r, d col nt*32+l31 (C/D layout)
            unsigned short* ob = att2 + ((size_t)bh * 2048 + qmin) * 64;
            #pragma unroll
            for (int g = 0; g < 4; ++g)
                #pragma unroll
                for (int r = 0; r < 4; ++r) {
                    const int qy = 8 * g + 4 * h + r;
                    const float iv = __shfl(inv, qy);
                    #pragma unroll
                    for (int nt = 0; nt < 2; ++nt)
                        ob[(size_t)qy * 64 + nt * 32 + l31] = f2bf(O[nt][4 * g + r] * iv);
                }
        }
    }
}

// ---------------------------------------------------------------------------
// Output projection: A in [b][h][t][64] layout, Wp^T [n][e], fp32 out + bias.
// 128x128 tiles, global_load_lds. grid (64, 8), block 256.
// ---------------------------------------------------------------------------
__global__ __launch_bounds__(256) void proj_gemm(
    const unsigned short* __restrict__ A,    // att2 bf16 [b*16+h][t][64]
    const unsigned short* __restrict__ wpt,
    const float* __restrict__ bp,
    float* __restrict__ out)
{
    __shared__ __align__(16) unsigned short sm[16384];
    unsigned short* As = sm;
    unsigned short* Bs = sm + 8192;

    const int tid = threadIdx.x;
    const int w = tid >> 6, lane = tid & 63, l15 = lane & 15, quad = lane >> 4;
    const int m0 = blockIdx.x * 128;
    const int n0 = blockIdx.y * 128;

    f32x4 acc[2][8];
    #pragma unroll
    for (int s = 0; s < 2; ++s)
        #pragma unroll
        for (int n = 0; n < 8; ++n) acc[s][n] = (f32x4){0.f, 0.f, 0.f, 0.f};

    // A element (m,k) at A[((m>>11)*16 + (k>>6))*131072 + (m&2047)*64 + (k&63)]
    const unsigned short* Ag = A + (size_t)(m0 >> 11) * 16 * 131072
                                 + (size_t)((m0 & 2047) + 32 * w + (lane >> 3)) * 64 + (lane & 7) * 8;
    const unsigned short* Bg = wpt + (size_t)(n0 + 32 * w + (lane >> 3)) * 1024 + (lane & 7) * 8;
    unsigned short* Al = As + (32 * w) * 64;
    unsigned short* Bl = Bs + (32 * w) * 64;

    for (int k0 = 0; k0 < 1024; k0 += 64) {
        __syncthreads();
        const size_t aoff = (size_t)(k0 >> 6) * 131072;
        #pragma unroll
        for (int j = 0; j < 4; ++j) {
            GLD(Ag + aoff + (size_t)(8 * j) * 64, Al + (8 * j) * 64);
            GLD(Bg + (size_t)(8 * j) * 1024 + k0, Bl + (8 * j) * 64);
        }
        __syncthreads();
        #pragma unroll
        for (int ks = 0; ks < 2; ++ks) {
            bf16x8 a0 = *(const bf16x8*)&As[(32 * w + l15) * 64 + ks * 32 + quad * 8];
            bf16x8 a1 = *(const bf16x8*)&As[(32 * w + 16 + l15) * 64 + ks * 32 + quad * 8];
            #pragma unroll
            for (int n = 0; n < 8; ++n) {
                bf16x8 b = *(const bf16x8*)&Bs[(16 * n + l15) * 64 + ks * 32 + quad * 8];
                acc[0][n] = __builtin_amdgcn_mfma_f32_16x16x32_bf16(a0, b, acc[0][n], 0, 0, 0);
                acc[1][n] = __builtin_amdgcn_mfma_f32_16x16x32_bf16(a1, b, acc[1][n], 0, 0, 0);
            }
        }
    }

    #pragma unroll
    for (int s = 0; s < 2; ++s)
        #pragma unroll
        for (int n = 0; n < 8; ++n) {
            float bi = bp[n0 + 16 * n + l15];
            #pragma unroll
            for (int r = 0; r < 4; ++r) {
                int row = m0 + 32 * w + 16 * s + quad * 4 + r;
                out[(size_t)row * 1024 + n0 + 16 * n + l15] = acc[s][n][r] + bi;
            }
        }
}

extern "C" void kernel_launch(void* const* d_in, const int* in_sizes, int n_in,
                              void* d_out, int out_size, void* d_ws, size_t ws_size,
                              hipStream_t stream) {
    const float* x  = (const float*)d_in[0];
    const float* Wq = (const float*)d_in[1];
    const float* Wk = (const float*)d_in[2];
    const float* Wv = (const float*)d_in[3];
    const float* bq = (const float*)d_in[4];
    const float* bk = (const float*)d_in[5];
    const float* bv = (const float*)d_in[6];
    const float* Wp = (const float*)d_in[7];
    const float* bp = (const float*)d_in[8];
    float* out = (float*)d_out;

    const size_t nx = (size_t)B_ * T_ * E_;
    unsigned short* base = (unsigned short*)d_ws;
    unsigned short* xb  = base;
    unsigned short* qb  = xb + nx;
    unsigned short* kb  = qb + nx;
    unsigned short* vtb = kb + nx;
    unsigned short* atb = vtb + nx;          // [bh][t][64]
    unsigned short* wf  = atb + nx;          // [3072][1024]
    unsigned short* wpt = wf + 3072 * 1024;  // [1024][1024]

    cast_x_kernel<<<(int)(nx / 4 + 255) / 256, 256, 0, stream>>>(x, xb, (int)(nx / 4));
    tcast_all<<<dim3(16, 64), 256, 0, stream>>>(Wq, Wk, Wv, Wp, wf, wpt);
    qkv_gemm<<<dim3(32, 12), 512, 0, stream>>>(xb, wf, bq, bk, bv, qb, kb, vtb);
    attn_kernel<<<dim3(64, 16), 256, 0, stream>>>(qb, kb, vtb, atb);
    proj_gemm<<<dim3(64, 8), 256, 0, stream>>>(atb, wpt, bp, out);
}

// Round 6
// 276.817 us; speedup vs baseline: 1.0037x; 1.0037x over previous
//
#include <hip/hip_runtime.h>
#include <math.h>

#define B_ 4
#define T_ 2048
#define E_ 1024
#define H_ 16
#define D_ 64

typedef __bf16 bf16_t;
typedef bf16_t bf16x8 __attribute__((ext_vector_type(8)));
typedef float  f32x4  __attribute__((ext_vector_type(4)));
typedef float  f32x16 __attribute__((ext_vector_type(16)));
typedef unsigned short u16x4 __attribute__((ext_vector_type(4)));
typedef unsigned int   u32x4 __attribute__((ext_vector_type(4)));

static __device__ __forceinline__ unsigned short f2bf(float f) {
    bf16_t h = (bf16_t)f;
    return __builtin_bit_cast(unsigned short, h);
}
static __device__ __forceinline__ unsigned int pk2(float a, float b) {
    return (unsigned int)f2bf(a) | ((unsigned int)f2bf(b) << 16);
}

// async global->LDS, 16B per lane; lds base wave-uniform + lane*16
#define GLD(gp, lp) __builtin_amdgcn_global_load_lds( \
    (const __attribute__((address_space(1))) unsigned int*)(gp), \
    (__attribute__((address_space(3))) unsigned int*)(lp), 16, 0, 0)

#define BAR() __builtin_amdgcn_s_barrier()
#define WAIT_LGKM0() asm volatile("s_waitcnt lgkmcnt(0)" ::: "memory")

// ---------------------------------------------------------------------------
// x fp32 -> bf16
// ---------------------------------------------------------------------------
__global__ void cast_x_kernel(const float* __restrict__ in, unsigned short* __restrict__ out, int n4) {
    int i = blockIdx.x * blockDim.x + threadIdx.x;
    if (i >= n4) return;
    float4 v = ((const float4*)in)[i];
    ushort4 o;
    o.x = f2bf(v.x); o.y = f2bf(v.y); o.z = f2bf(v.z); o.w = f2bf(v.w);
    ((ushort4*)out)[i] = o;
}

// ---------------------------------------------------------------------------
// fused transpose-cast for all 4 weights. grid (16, 64), block 256.
// grp 0..2: Wq/Wk/Wv [h][e][d] -> wf[(grp*1024+h*64+d)][e]; grp 3: Wp [e][n] -> wpt[n][e]
// ---------------------------------------------------------------------------
__global__ void tcast_all(const float* __restrict__ Wq, const float* __restrict__ Wk,
                          const float* __restrict__ Wv, const float* __restrict__ Wp,
                          unsigned short* __restrict__ wf, unsigned short* __restrict__ wpt) {
    __shared__ unsigned short Ts[64 * 66];
    const int grp = blockIdx.y >> 4, yy = blockIdx.y & 15;
    const float* in; unsigned short* out; int yA, S;
    if (grp == 3) { in = Wp; out = wpt; yA = 64;    S = 1024; }
    else {
        in = (grp == 0) ? Wq : (grp == 1) ? Wk : Wv;
        out = wf + (size_t)grp * 1024 * 1024; yA = 65536; S = 64;
    }
    const int tid = threadIdx.x;
    const int r = tid >> 2, c4 = tid & 3;
    const float* ip = in + (size_t)yA * yy + (size_t)(blockIdx.x * 64 + r) * S + c4 * 16;
    #pragma unroll
    for (int j = 0; j < 4; ++j) {
        float4 v = *(const float4*)&ip[j * 4];
        Ts[(c4 * 16 + j * 4 + 0) * 66 + r] = f2bf(v.x);
        Ts[(c4 * 16 + j * 4 + 1) * 66 + r] = f2bf(v.y);
        Ts[(c4 * 16 + j * 4 + 2) * 66 + r] = f2bf(v.z);
        Ts[(c4 * 16 + j * 4 + 3) * 66 + r] = f2bf(v.w);
    }
    __syncthreads();
    unsigned short* op = out + (size_t)(yy * 64 + r) * 1024 + blockIdx.x * 64 + c4 * 16;
    #pragma unroll
    for (int j = 0; j < 4; ++j) {
        u16x4 pk;
        #pragma unroll
        for (int m = 0; m < 4; ++m) pk[m] = Ts[r * 66 + c4 * 16 + j * 4 + m];
        *(u16x4*)&op[j * 4] = pk;
    }
}

// ---------------------------------------------------------------------------
// Fused QKV GEMM: [8192 x 1024] x [3072 x 1024]^T.
// 256x256 tile, 512 threads (8 waves 2Mx4N), 8-phase schedule, BK=64,
// 1 half-tile (2 GLD) staged per phase, vmcnt(4) at P4/P8 only, 128KB LDS
// double-buffer, T2 swizzle via pre-swizzled global source (rule 21).
// STAGING LEDGER (verified race-free, round 4):
//   P1:A0(t1) P2:A1(t1) P3:B0(t0+2) P4:B1(t0+2)+vmcnt(4)
//   P5:A0(t0+2) P6:A1(t0+2) P7:B0(t1+2) P8:B1(t1+2)+vmcnt(4)
// q scaled 0.125 (+bias); k +bias; v (+bias) stored transposed [bh][64][T].
// grid (32, 12), block 512.
// ---------------------------------------------------------------------------
__global__ __launch_bounds__(512, 2) void qkv_gemm(
    const unsigned short* __restrict__ xb,
    const unsigned short* __restrict__ wf,
    const float* __restrict__ bq, const float* __restrict__ bk, const float* __restrict__ bv,
    unsigned short* __restrict__ qo, unsigned short* __restrict__ ko,
    unsigned short* __restrict__ vt)
{
    // buf q at sm + q*32768 (u16): A0 @0, A1 @8192, B0 @16384, B1 @24576
    __shared__ __align__(16) unsigned short sm[65536];   // 128 KiB

    const int tid = threadIdx.x;
    const int w = tid >> 6, lane = tid & 63;
    const int wr = w >> 2, wc = w & 3;                  // wave -> (Mhalf, Nquarter)
    const int l15 = lane & 15, quad = lane >> 4, lsw = l15 & 7;
    const int m0 = blockIdx.x * 256;
    const int n0 = blockIdx.y * 256;

    f32x4 acc[8][4];
    #pragma unroll
    for (int i = 0; i < 8; ++i)
        #pragma unroll
        for (int j = 0; j < 4; ++j) acc[i][j] = (f32x4){0.f, 0.f, 0.f, 0.f};

    // T2: linear GLD dest + inverse-swizzled global source (rule 21).
    const int swzE = (((lane & 7) ^ (lane >> 3)) * 8);
    const unsigned short* Agb = xb + (size_t)(m0 + w * 16 + (lane >> 3)) * 1024 + swzE;
    const unsigned short* Bgb = wf + (size_t)(n0 + w * 16 + (lane >> 3)) * 1024 + swzE;

    // stage one half-tile (2 GLD/thread): which 0=A0 1=A1 2=B0 3=B1, tile t
    auto stage_half = [&](int t, int which) {
        unsigned short* dst = sm + (t & 1) * 32768 + which * 8192 + w * 1024;
        const unsigned short* src = ((which < 2) ? Agb : Bgb)
                                  + (size_t)((which & 1) * 128) * 1024 + t * 64;
        GLD(src, dst);
        GLD(src + (size_t)8 * 1024, dst + 512);
    };
    // swizzled fragment reads: slot c of row r lives at slot c^(r&7); r&7==l15&7
    auto rdA = [&](int t, int fm, int ks) {
        const int row = wr * 128 + fm * 16 + l15;
        return *(const bf16x8*)&sm[(t & 1) * 32768 + (row >> 7) * 8192
                                   + (row & 127) * 64 + (((ks * 4 + quad) ^ lsw) * 8)];
    };
    auto rdB = [&](int t, int fn, int ks) {
        const int row = wc * 64 + fn * 16 + l15;
        return *(const bf16x8*)&sm[(t & 1) * 32768 + 16384 + (row >> 7) * 8192
                                   + (row & 127) * 64 + (((ks * 4 + quad) ^ lsw) * 8)];
    };

    // prologue: tile0 all 4 halves + tile1 {B0,B1}; A0/A1(t1) staged at P1/P2.
    stage_half(0, 0); stage_half(0, 1); stage_half(0, 2); stage_half(0, 3);
    stage_half(1, 2); stage_half(1, 3);
    asm volatile("s_waitcnt vmcnt(4)" ::: "memory");
    BAR();

    #define MFMA_Q(mb, nb) \
        __builtin_amdgcn_s_setprio(1); \
        _Pragma("unroll") \
        for (int i_ = 0; i_ < 4; ++i_) \
            _Pragma("unroll") \
            for (int j_ = 0; j_ < 2; ++j_) \
                _Pragma("unroll") \
                for (int ks_ = 0; ks_ < 2; ++ks_) \
                    acc[(mb) + i_][(nb) + j_] = __builtin_amdgcn_mfma_f32_16x16x32_bf16( \
                        fA[i_][ks_], fB[(nb) + j_][ks_], acc[(mb) + i_][(nb) + j_], 0, 0, 0); \
        __builtin_amdgcn_s_setprio(0);

    #pragma unroll 1
    for (int it = 0; it < 8; ++it) {
        const int t0 = 2 * it, t1 = 2 * it + 1;
        const bool more = it < 7;
        bf16x8 fA[4][2], fB[4][2];

        // ---- P1: reads fm0-3 + fn0-1 of t0 (12); stage A0(t1)
        #pragma unroll
        for (int m = 0; m < 4; ++m) { fA[m][0] = rdA(t0, m, 0); fA[m][1] = rdA(t0, m, 1); }
        #pragma unroll
        for (int n = 0; n < 2; ++n) { fB[n][0] = rdB(t0, n, 0); fB[n][1] = rdB(t0, n, 1); }
        stage_half(t1, 0);
        BAR(); WAIT_LGKM0();
        MFMA_Q(0, 0);
        BAR();

        // ---- P2: reads fn2-3 of t0 (4); stage A1(t1)
        #pragma unroll
        for (int n = 0; n < 2; ++n) { fB[2 + n][0] = rdB(t0, 2 + n, 0); fB[2 + n][1] = rdB(t0, 2 + n, 1); }
        stage_half(t1, 1);
        BAR(); WAIT_LGKM0();
        MFMA_Q(0, 2);
        BAR();

        // ---- P3: reads fm4-7 of t0 (8); stage B0(t0+2)  [B(t0) last read P2]
        #pragma unroll
        for (int m = 0; m < 4; ++m) { fA[m][0] = rdA(t0, 4 + m, 0); fA[m][1] = rdA(t0, 4 + m, 1); }
        if (more) stage_half(t0 + 2, 2);
        BAR(); WAIT_LGKM0();
        MFMA_Q(4, 2);
        BAR();

        // ---- P4: no reads; stage B1(t0+2); vmcnt(4) -> t1 fully landed
        if (more) {
            stage_half(t0 + 2, 3);
            asm volatile("s_waitcnt vmcnt(4)" ::: "memory");
        } else {
            asm volatile("s_waitcnt vmcnt(0)" ::: "memory");
        }
        BAR();
        MFMA_Q(4, 0);
        BAR();

        // ---- P5: reads fm0-3 + fn0-1 of t1 (12); stage A0(t0+2)  [A(t0) last read P3]
        #pragma unroll
        for (int m = 0; m < 4; ++m) { fA[m][0] = rdA(t1, m, 0); fA[m][1] = rdA(t1, m, 1); }
        #pragma unroll
        for (int n = 0; n < 2; ++n) { fB[n][0] = rdB(t1, n, 0); fB[n][1] = rdB(t1, n, 1); }
        if (more) stage_half(t0 + 2, 0);
        BAR(); WAIT_LGKM0();
        MFMA_Q(0, 0);
        BAR();

        // ---- P6: reads fn2-3 of t1 (4); stage A1(t0+2)
        #pragma unroll
        for (int n = 0; n < 2; ++n) { fB[2 + n][0] = rdB(t1, 2 + n, 0); fB[2 + n][1] = rdB(t1, 2 + n, 1); }
        if (more) stage_half(t0 + 2, 1);
        BAR(); WAIT_LGKM0();
        MFMA_Q(0, 2);
        BAR();

        // ---- P7: reads fm4-7 of t1 (8); stage B0(t1+2)  [B(t1) last read P6]
        #pragma unroll
        for (int m = 0; m < 4; ++m) { fA[m][0] = rdA(t1, 4 + m, 0); fA[m][1] = rdA(t1, 4 + m, 1); }
        if (more) stage_half(t1 + 2, 2);
        BAR(); WAIT_LGKM0();
        MFMA_Q(4, 2);
        BAR();

        // ---- P8: no reads; stage B1(t1+2); vmcnt(4) -> t0+2 fully landed
        if (more) {
            stage_half(t1 + 2, 3);
            asm volatile("s_waitcnt vmcnt(4)" ::: "memory");
        } else {
            asm volatile("s_waitcnt vmcnt(0)" ::: "memory");
        }
        BAR();
        MFMA_Q(4, 0);
        BAR();
    }
    #undef MFMA_Q

    const int which = n0 >> 10;           // 256-wide N-tile lies in one of q/k/v
    const int nb = n0 & 1023;
    if (which < 2) {
        const float* bias = which ? bk : bq;
        unsigned short* outp = which ? ko : qo;
        const float sc = which ? 1.f : 0.125f;
        #pragma unroll
        for (int fm = 0; fm < 8; ++fm)
            #pragma unroll
            for (int fn = 0; fn < 4; ++fn) {
                int colg = nb + wc * 64 + fn * 16 + l15;
                int h = colg >> 6, d = colg & 63;
                float bi = bias[colg];
                #pragma unroll
                for (int r = 0; r < 4; ++r) {
                    int row = m0 + wr * 128 + fm * 16 + quad * 4 + r;
                    int b = row >> 11, t = row & 2047;
                    outp[(((size_t)b * 16 + h) * 2048 + t) * 64 + d] = f2bf((acc[fm][fn][r] + bi) * sc);
                }
            }
    } else {
        // V: transpose via LDS, 4 sub-blocks of 128(m) x 128(n), padded stride 136
        const int b = m0 >> 11;
        for (int mh = 0; mh < 2; ++mh)
            for (int nh = 0; nh < 2; ++nh) {
                __syncthreads();
                if (wr == mh && (wc >> 1) == nh) {
                    const int cc = wc & 1;
                    #pragma unroll
                    for (int fm = 0; fm < 8; ++fm)
                        #pragma unroll
                        for (int fn = 0; fn < 4; ++fn) {
                            int colL = cc * 64 + fn * 16 + l15;          // 0..127
                            int colg = nb + nh * 128 + colL;
                            float bi = bv[colg];
                            u16x4 pk;
                            #pragma unroll
                            for (int r = 0; r < 4; ++r) pk[r] = f2bf(acc[fm][fn][r] + bi);
                            *(u16x4*)&sm[colL * 136 + fm * 16 + quad * 4] = pk;
                        }
                }
                __syncthreads();
                const int nl = tid >> 2, tq = tid & 3;                   // col 0..127, quarter
                const int colg = nb + nh * 128 + nl;
                const int h = colg >> 6, d = colg & 63;
                const int t0 = (m0 & 2047) + mh * 128;
                unsigned short* dst = vt + (((size_t)b * 16 + h) * 64 + d) * 2048 + t0 + tq * 32;
                #pragma unroll
                for (int j = 0; j < 4; ++j)
                    *(float4*)&dst[j * 8] = *(const float4*)&sm[nl * 136 + tq * 32 + j * 8];
            }
    }
}

// ---------------------------------------------------------------------------
// Flash attention v3: round-4 decomposition (128 q/block, wave owns 32 q x
// all keys) + async double-buffered K/V staging + in-register P.
// q pre-scaled 1/8 [bh][t][64]; k [bh][t][64]; v transposed [bh][64][T].
// Per trip (64 keys): issue 4 global_load_lds for tile jt+1 (pre-swizzled
// global source, linear LDS dest - rule 21), compute tile jt from buf jt&1,
// vmcnt(0) + ONE barrier at trip end (HBM latency hides under compute).
// P never touches LDS: swapped QK^T keeps keys lane-local; the h<->h+32
// fragment exchange uses __shfl_xor(32) (HW-validated round 5), per kt tile.
// Legs pair q-tiles (p, 15-p) => every block exactly 34 trips.
// grid (64 bh, 8 pairs), block 256 (4 waves). LDS 32KB (2x(K+V)), no Ps.
// C/D layout (verified): col=lane&31, row=(reg&3)+8*(reg>>2)+4*(lane>>5).
// ---------------------------------------------------------------------------
__global__ __launch_bounds__(256, 4) void attn_kernel(
    const unsigned short* __restrict__ q, const unsigned short* __restrict__ k,
    const unsigned short* __restrict__ vt, unsigned short* __restrict__ att2)
{
    // [buf][0]=K rows=key, [buf][1]=V^T rows=d; 64x64 bf16 each, XOR-swizzled
    __shared__ __align__(16) unsigned short KV[2][2][4096];

    const int tid = threadIdx.x;
    const int w = tid >> 6, lane = tid & 63;
    const int l31 = lane & 31, h = lane >> 5;
    const int bh = blockIdx.x;
    const int rs = l31 & 7;

    const unsigned short* kb = k  + (size_t)bh * 2048 * 64;
    const unsigned short* vb = vt + (size_t)bh * 64 * 2048;

    // staging: wave w stages rows 16w..16w+15 of K and V^T via GLD.
    // LDS slot lane&7 of row 16w+(lane>>3) <- global chunk (lane&7)^(lane>>3);
    // (row&7) == (lane>>3)&7 for both 8-row groups, so read-side XOR matches.
    const int swz = ((lane & 7) ^ (lane >> 3)) * 8;
    const unsigned short* Kg = kb + (size_t)(16 * w + (lane >> 3)) * 64 + swz;
    const unsigned short* Vg = vb + (size_t)(16 * w + (lane >> 3)) * 2048 + swz;

    for (int leg = 0; leg < 2; ++leg) {
        const int qtile = leg ? (15 - (int)blockIdx.y) : (int)blockIdx.y;
        const int qb0 = qtile * 128;
        const int qmin = qb0 + w * 32, qmax = qmin + 31;
        const int qg = qmin + l31;             // query owned as S^T COLUMN
        const int trips = 2 * qtile + 2;

        // Q B-fragments straight from global: B[k=d][n=query]
        bf16x8 fQ[4];
        {
            const unsigned short* qp = q + ((size_t)bh * 2048 + qg) * 64 + h * 8;
            #pragma unroll
            for (int ks = 0; ks < 4; ++ks) fQ[ks] = *(const bf16x8*)&qp[ks * 16];
        }

        f32x16 O[2];
        #pragma unroll
        for (int nt = 0; nt < 2; ++nt)
            #pragma unroll
            for (int i = 0; i < 16; ++i) O[nt][i] = 0.f;
        float lsum = 0.f;

        // prologue: stage tile 0 -> buf 0
        {
            unsigned short* dK = &KV[0][0][w * 1024];
            unsigned short* dV = &KV[0][1][w * 1024];
            GLD(Kg, dK); GLD(Kg + 512, dK + 512);
            GLD(Vg, dV); GLD(Vg + 8 * 2048, dV + 512);
        }
        asm volatile("s_waitcnt vmcnt(0)" ::: "memory");
        BAR();

        for (int jt = 0; jt < trips; ++jt) {
            const int buf = jt & 1;
            // issue next tile's staging into the other buffer (read out at jt-1)
            if (jt + 1 < trips) {
                unsigned short* dK = &KV[buf ^ 1][0][w * 1024];
                unsigned short* dV = &KV[buf ^ 1][1][w * 1024];
                const unsigned short* sK = Kg + (size_t)(jt + 1) * 4096;
                const unsigned short* sV = Vg + (jt + 1) * 64;
                GLD(sK, dK); GLD(sK + 512, dK + 512);
                GLD(sV, dV); GLD(sV + 8 * 2048, dV + 512);
            }
            const unsigned short* Ks = KV[buf][0];
            const unsigned short* Vs = KV[buf][1];

            const int key0 = jt * 64;
            if (key0 <= qmax) {   // wave-uniform: skip fully-masked tiles
                // S^T = K . Q^T : M=key(2 tiles of 32), N=query, K-dim=d
                f32x16 S[2];
                #pragma unroll
                for (int kt = 0; kt < 2; ++kt)
                    #pragma unroll
                    for (int i = 0; i < 16; ++i) S[kt][i] = 0.f;
                __builtin_amdgcn_s_setprio(1);
                #pragma unroll
                for (int kt = 0; kt < 2; ++kt) {
                    const int row = kt * 32 + l31;
                    #pragma unroll
                    for (int ks = 0; ks < 4; ++ks) {
                        bf16x8 aK = *(const bf16x8*)&Ks[row * 64 + ((2 * ks + h) ^ rs) * 8];
                        S[kt] = __builtin_amdgcn_mfma_f32_32x32x16_bf16(aK, fQ[ks], S[kt], 0, 0, 0);
                    }
                }
                __builtin_amdgcn_s_setprio(0);

                // S^T element (kt,4g+r): key = key0+32kt+8g+4h+r, query col qg.
                // softmax (no-max: |S| bounded) -> packed bf16 pairs in regs
                const bool need_mask = (key0 + 63) > qmin;
                unsigned int e0[2][4], e1[2][4];
                #pragma unroll
                for (int kt = 0; kt < 2; ++kt)
                    #pragma unroll
                    for (int g = 0; g < 4; ++g) {
                        float p[4];
                        #pragma unroll
                        for (int r = 0; r < 4; ++r) {
                            float pv = __expf(S[kt][4 * g + r]);
                            if (need_mask) {
                                int key = key0 + kt * 32 + 8 * g + 4 * h + r;
                                if (key > qg) pv = 0.f;
                            }
                            p[r] = pv;
                            lsum += pv;
                        }
                        e0[kt][g] = pk2(p[0], p[1]);
                        e1[kt][g] = pk2(p[2], p[3]);
                    }

                // O += P.V : per slice ks2, A-fragment needs keys
                // 32kt+16s+8h+{0..7}; build via half-wave exchange (validated r5)
                __builtin_amdgcn_s_setprio(1);
                #pragma unroll
                for (int ks2 = 0; ks2 < 4; ++ks2) {
                    const int kt = ks2 >> 1, s = ks2 & 1;
                    const int ge = 2 * s, go = 2 * s + 1;
                    unsigned int own0 = h ? e0[kt][go] : e0[kt][ge];
                    unsigned int snd0 = h ? e0[kt][ge] : e0[kt][go];
                    unsigned int rcv0 = (unsigned int)__shfl_xor((int)snd0, 32);
                    unsigned int own1 = h ? e1[kt][go] : e1[kt][ge];
                    unsigned int snd1 = h ? e1[kt][ge] : e1[kt][go];
                    unsigned int rcv1 = (unsigned int)__shfl_xor((int)snd1, 32);
                    u32x4 t;
                    t[0] = h ? rcv0 : own0;   // keys +0,+1
                    t[1] = h ? rcv1 : own1;   // keys +2,+3
                    t[2] = h ? own0 : rcv0;   // keys +4,+5
                    t[3] = h ? own1 : rcv1;   // keys +6,+7
                    bf16x8 aP = __builtin_bit_cast(bf16x8, t);
                    #pragma unroll
                    for (int nt = 0; nt < 2; ++nt) {
                        const int drow = nt * 32 + l31;
                        bf16x8 bV = *(const bf16x8*)&Vs[drow * 64 + ((2 * ks2 + h) ^ rs) * 8];
                        O[nt] = __builtin_amdgcn_mfma_f32_32x32x16_bf16(aP, bV, O[nt], 0, 0, 0);
                    }
                }
                __builtin_amdgcn_s_setprio(0);
            }

            asm volatile("s_waitcnt vmcnt(0)" ::: "memory");   // next tile landed
            BAR();
        }

        // lsum lives split across half-waves (query qg in lanes l31 and l31+32)
        lsum += __shfl_xor(lsum, 32);
        const float inv = 1.f / lsum;

        // O[nt][4g+r]: query row 8g+4h+r, d col nt*32+l31 (C/D layout)
        unsigned short* ob = att2 + ((size_t)bh * 2048 + qmin) * 64;
        #pragma unroll
        for (int g = 0; g < 4; ++g)
            #pragma unroll
            for (int r = 0; r < 4; ++r) {
                const int qy = 8 * g + 4 * h + r;
                const float iv = __shfl(inv, qy);
                #pragma unroll
                for (int nt = 0; nt < 2; ++nt)
                    ob[(size_t)qy * 64 + nt * 32 + l31] = f2bf(O[nt][4 * g + r] * iv);
            }
    }
}

// ---------------------------------------------------------------------------
// Output projection: A in [b][h][t][64] layout, Wp^T [n][e], fp32 out + bias.
// 128x128 tiles, global_load_lds. grid (64, 8), block 256.
// ---------------------------------------------------------------------------
__global__ __launch_bounds__(256) void proj_gemm(
    const unsigned short* __restrict__ A,    // att2 bf16 [b*16+h][t][64]
    const unsigned short* __restrict__ wpt,
    const float* __restrict__ bp,
    float* __restrict__ out)
{
    __shared__ __align__(16) unsigned short sm[16384];
    unsigned short* As = sm;
    unsigned short* Bs = sm + 8192;

    const int tid = threadIdx.x;
    const int w = tid >> 6, lane = tid & 63, l15 = lane & 15, quad = lane >> 4;
    const int m0 = blockIdx.x * 128;
    const int n0 = blockIdx.y * 128;

    f32x4 acc[2][8];
    #pragma unroll
    for (int s = 0; s < 2; ++s)
        #pragma unroll
        for (int n = 0; n < 8; ++n) acc[s][n] = (f32x4){0.f, 0.f, 0.f, 0.f};

    // A element (m,k) at A[((m>>11)*16 + (k>>6))*131072 + (m&2047)*64 + (k&63)]
    const unsigned short* Ag = A + (size_t)(m0 >> 11) * 16 * 131072
                                 + (size_t)((m0 & 2047) + 32 * w + (lane >> 3)) * 64 + (lane & 7) * 8;
    const unsigned short* Bg = wpt + (size_t)(n0 + 32 * w + (lane >> 3)) * 1024 + (lane & 7) * 8;
    unsigned short* Al = As + (32 * w) * 64;
    unsigned short* Bl = Bs + (32 * w) * 64;

    for (int k0 = 0; k0 < 1024; k0 += 64) {
        __syncthreads();
        const size_t aoff = (size_t)(k0 >> 6) * 131072;
        #pragma unroll
        for (int j = 0; j < 4; ++j) {
            GLD(Ag + aoff + (size_t)(8 * j) * 64, Al + (8 * j) * 64);
            GLD(Bg + (size_t)(8 * j) * 1024 + k0, Bl + (8 * j) * 64);
        }
        __syncthreads();
        #pragma unroll
        for (int ks = 0; ks < 2; ++ks) {
            bf16x8 a0 = *(const bf16x8*)&As[(32 * w + l15) * 64 + ks * 32 + quad * 8];
            bf16x8 a1 = *(const bf16x8*)&As[(32 * w + 16 + l15) * 64 + ks * 32 + quad * 8];
            #pragma unroll
            for (int n = 0; n < 8; ++n) {
                bf16x8 b = *(const bf16x8*)&Bs[(16 * n + l15) * 64 + ks * 32 + quad * 8];
                acc[0][n] = __builtin_amdgcn_mfma_f32_16x16x32_bf16(a0, b, acc[0][n], 0, 0, 0);
                acc[1][n] = __builtin_amdgcn_mfma_f32_16x16x32_bf16(a1, b, acc[1][n], 0, 0, 0);
            }
        }
    }

    #pragma unroll
    for (int s = 0; s < 2; ++s)
        #pragma unroll
        for (int n = 0; n < 8; ++n) {
            float bi = bp[n0 + 16 * n + l15];
            #pragma unroll
            for (int r = 0; r < 4; ++r) {
                int row = m0 + 32 * w + 16 * s + quad * 4 + r;
                out[(size_t)row * 1024 + n0 + 16 * n + l15] = acc[s][n][r] + bi;
            }
        }
}

extern "C" void kernel_launch(void* const* d_in, const int* in_sizes, int n_in,
                              void* d_out, int out_size, void* d_ws, size_t ws_size,
                              hipStream_t stream) {
    const float* x  = (const float*)d_in[0];
    const float* Wq = (const float*)d_in[1];
    const float* Wk = (const float*)d_in[2];
    const float* Wv = (const float*)d_in[3];
    const float* bq = (const float*)d_in[4];
    const float* bk = (const float*)d_in[5];
    const float* bv = (const float*)d_in[6];
    const float* Wp = (const float*)d_in[7];
    const float* bp = (const float*)d_in[8];
    float* out = (float*)d_out;

    const size_t nx = (size_t)B_ * T_ * E_;
    unsigned short* base = (unsigned short*)d_ws;
    unsigned short* xb  = base;
    unsigned short* qb  = xb + nx;
    unsigned short* kb  = qb + nx;
    unsigned short* vtb = kb + nx;
    unsigned short* atb = vtb + nx;          // [bh][t][64]
    unsigned short* wf  = atb + nx;          // [3072][1024]
    unsigned short* wpt = wf + 3072 * 1024;  // [1024][1024]

    cast_x_kernel<<<(int)(nx / 4 + 255) / 256, 256, 0, stream>>>(x, xb, (int)(nx / 4));
    tcast_all<<<dim3(16, 64), 256, 0, stream>>>(Wq, Wk, Wv, Wp, wf, wpt);
    qkv_gemm<<<dim3(32, 12), 512, 0, stream>>>(xb, wf, bq, bk, bv, qb, kb, vtb);
    attn_kernel<<<dim3(64, 8), 256, 0, stream>>>(qb, kb, vtb, atb);
    proj_gemm<<<dim3(64, 8), 256, 0, stream>>>(atb, wpt, bp, out);
}

// Round 7
// 269.594 us; speedup vs baseline: 1.0305x; 1.0268x over previous
//
#include <hip/hip_runtime.h>
#include <math.h>

#define B_ 4
#define T_ 2048
#define E_ 1024
#define H_ 16
#define D_ 64

typedef __bf16 bf16_t;
typedef bf16_t bf16x8 __attribute__((ext_vector_type(8)));
typedef float  f32x4  __attribute__((ext_vector_type(4)));
typedef float  f32x16 __attribute__((ext_vector_type(16)));
typedef unsigned short u16x4 __attribute__((ext_vector_type(4)));
typedef unsigned int   u32x4 __attribute__((ext_vector_type(4)));

static __device__ __forceinline__ unsigned short f2bf(float f) {
    bf16_t h = (bf16_t)f;
    return __builtin_bit_cast(unsigned short, h);
}
static __device__ __forceinline__ unsigned int pk2(float a, float b) {
    return (unsigned int)f2bf(a) | ((unsigned int)f2bf(b) << 16);
}
// native 2^x (q is pre-scaled by 0.125*log2e so this computes e^(orig S))
static __device__ __forceinline__ float ex2(float x) {
    float r; asm("v_exp_f32 %0, %1" : "=v"(r) : "v"(x)); return r;
}
// v_permlane32_swap_b32: a' = {a.row0, b.row0}, b' = {a.row1, b.row1}
static __device__ __forceinline__ void pl32swap(unsigned int& a, unsigned int& b) {
    asm("v_permlane32_swap_b32 %0, %1" : "+v"(a), "+v"(b));
}

// async global->LDS, 16B per lane; lds base wave-uniform + lane*16
#define GLD(gp, lp) __builtin_amdgcn_global_load_lds( \
    (const __attribute__((address_space(1))) unsigned int*)(gp), \
    (__attribute__((address_space(3))) unsigned int*)(lp), 16, 0, 0)

#define BAR() __builtin_amdgcn_s_barrier()
#define WAIT_LGKM0() asm volatile("s_waitcnt lgkmcnt(0)" ::: "memory")

// ---------------------------------------------------------------------------
// x fp32 -> bf16
// ---------------------------------------------------------------------------
__global__ void cast_x_kernel(const float* __restrict__ in, unsigned short* __restrict__ out, int n4) {
    int i = blockIdx.x * blockDim.x + threadIdx.x;
    if (i >= n4) return;
    float4 v = ((const float4*)in)[i];
    ushort4 o;
    o.x = f2bf(v.x); o.y = f2bf(v.y); o.z = f2bf(v.z); o.w = f2bf(v.w);
    ((ushort4*)out)[i] = o;
}

// ---------------------------------------------------------------------------
// fused transpose-cast for all 4 weights. grid (16, 64), block 256.
// grp 0..2: Wq/Wk/Wv [h][e][d] -> wf[(grp*1024+h*64+d)][e]; grp 3: Wp [e][n] -> wpt[n][e]
// ---------------------------------------------------------------------------
__global__ void tcast_all(const float* __restrict__ Wq, const float* __restrict__ Wk,
                          const float* __restrict__ Wv, const float* __restrict__ Wp,
                          unsigned short* __restrict__ wf, unsigned short* __restrict__ wpt) {
    __shared__ unsigned short Ts[64 * 66];
    const int grp = blockIdx.y >> 4, yy = blockIdx.y & 15;
    const float* in; unsigned short* out; int yA, S;
    if (grp == 3) { in = Wp; out = wpt; yA = 64;    S = 1024; }
    else {
        in = (grp == 0) ? Wq : (grp == 1) ? Wk : Wv;
        out = wf + (size_t)grp * 1024 * 1024; yA = 65536; S = 64;
    }
    const int tid = threadIdx.x;
    const int r = tid >> 2, c4 = tid & 3;
    const float* ip = in + (size_t)yA * yy + (size_t)(blockIdx.x * 64 + r) * S + c4 * 16;
    #pragma unroll
    for (int j = 0; j < 4; ++j) {
        float4 v = *(const float4*)&ip[j * 4];
        Ts[(c4 * 16 + j * 4 + 0) * 66 + r] = f2bf(v.x);
        Ts[(c4 * 16 + j * 4 + 1) * 66 + r] = f2bf(v.y);
        Ts[(c4 * 16 + j * 4 + 2) * 66 + r] = f2bf(v.z);
        Ts[(c4 * 16 + j * 4 + 3) * 66 + r] = f2bf(v.w);
    }
    __syncthreads();
    unsigned short* op = out + (size_t)(yy * 64 + r) * 1024 + blockIdx.x * 64 + c4 * 16;
    #pragma unroll
    for (int j = 0; j < 4; ++j) {
        u16x4 pk;
        #pragma unroll
        for (int m = 0; m < 4; ++m) pk[m] = Ts[r * 66 + c4 * 16 + j * 4 + m];
        *(u16x4*)&op[j * 4] = pk;
    }
}

// ---------------------------------------------------------------------------
// Fused QKV GEMM: [8192 x 1024] x [3072 x 1024]^T.
// 256x256 tile, 512 threads (8 waves 2Mx4N), 8-phase schedule, BK=64,
// 1 half-tile (2 GLD) staged per phase, vmcnt(4) at P4/P8 only, 128KB LDS
// double-buffer, T2 swizzle via pre-swizzled global source (rule 21).
// STAGING LEDGER (verified race-free, round 4):
//   P1:A0(t1) P2:A1(t1) P3:B0(t0+2) P4:B1(t0+2)+vmcnt(4)
//   P5:A0(t0+2) P6:A1(t0+2) P7:B0(t1+2) P8:B1(t1+2)+vmcnt(4)
// q scaled 0.125*log2e (exp2 folding, +bias); k +bias; v (+bias) transposed.
// grid (32, 12), block 512.
// ---------------------------------------------------------------------------
__global__ __launch_bounds__(512, 2) void qkv_gemm(
    const unsigned short* __restrict__ xb,
    const unsigned short* __restrict__ wf,
    const float* __restrict__ bq, const float* __restrict__ bk, const float* __restrict__ bv,
    unsigned short* __restrict__ qo, unsigned short* __restrict__ ko,
    unsigned short* __restrict__ vt)
{
    // buf q at sm + q*32768 (u16): A0 @0, A1 @8192, B0 @16384, B1 @24576
    __shared__ __align__(16) unsigned short sm[65536];   // 128 KiB

    const int tid = threadIdx.x;
    const int w = tid >> 6, lane = tid & 63;
    const int wr = w >> 2, wc = w & 3;                  // wave -> (Mhalf, Nquarter)
    const int l15 = lane & 15, quad = lane >> 4, lsw = l15 & 7;
    const int m0 = blockIdx.x * 256;
    const int n0 = blockIdx.y * 256;

    f32x4 acc[8][4];
    #pragma unroll
    for (int i = 0; i < 8; ++i)
        #pragma unroll
        for (int j = 0; j < 4; ++j) acc[i][j] = (f32x4){0.f, 0.f, 0.f, 0.f};

    // T2: linear GLD dest + inverse-swizzled global source (rule 21).
    const int swzE = (((lane & 7) ^ (lane >> 3)) * 8);
    const unsigned short* Agb = xb + (size_t)(m0 + w * 16 + (lane >> 3)) * 1024 + swzE;
    const unsigned short* Bgb = wf + (size_t)(n0 + w * 16 + (lane >> 3)) * 1024 + swzE;

    // stage one half-tile (2 GLD/thread): which 0=A0 1=A1 2=B0 3=B1, tile t
    auto stage_half = [&](int t, int which) {
        unsigned short* dst = sm + (t & 1) * 32768 + which * 8192 + w * 1024;
        const unsigned short* src = ((which < 2) ? Agb : Bgb)
                                  + (size_t)((which & 1) * 128) * 1024 + t * 64;
        GLD(src, dst);
        GLD(src + (size_t)8 * 1024, dst + 512);
    };
    // swizzled fragment reads: slot c of row r lives at slot c^(r&7); r&7==l15&7
    auto rdA = [&](int t, int fm, int ks) {
        const int row = wr * 128 + fm * 16 + l15;
        return *(const bf16x8*)&sm[(t & 1) * 32768 + (row >> 7) * 8192
                                   + (row & 127) * 64 + (((ks * 4 + quad) ^ lsw) * 8)];
    };
    auto rdB = [&](int t, int fn, int ks) {
        const int row = wc * 64 + fn * 16 + l15;
        return *(const bf16x8*)&sm[(t & 1) * 32768 + 16384 + (row >> 7) * 8192
                                   + (row & 127) * 64 + (((ks * 4 + quad) ^ lsw) * 8)];
    };

    // prologue: tile0 all 4 halves + tile1 {B0,B1}; A0/A1(t1) staged at P1/P2.
    stage_half(0, 0); stage_half(0, 1); stage_half(0, 2); stage_half(0, 3);
    stage_half(1, 2); stage_half(1, 3);
    asm volatile("s_waitcnt vmcnt(4)" ::: "memory");
    BAR();

    #define MFMA_Q(mb, nb) \
        __builtin_amdgcn_s_setprio(1); \
        _Pragma("unroll") \
        for (int i_ = 0; i_ < 4; ++i_) \
            _Pragma("unroll") \
            for (int j_ = 0; j_ < 2; ++j_) \
                _Pragma("unroll") \
                for (int ks_ = 0; ks_ < 2; ++ks_) \
                    acc[(mb) + i_][(nb) + j_] = __builtin_amdgcn_mfma_f32_16x16x32_bf16( \
                        fA[i_][ks_], fB[(nb) + j_][ks_], acc[(mb) + i_][(nb) + j_], 0, 0, 0); \
        __builtin_amdgcn_s_setprio(0);

    #pragma unroll 1
    for (int it = 0; it < 8; ++it) {
        const int t0 = 2 * it, t1 = 2 * it + 1;
        const bool more = it < 7;
        bf16x8 fA[4][2], fB[4][2];

        // ---- P1: reads fm0-3 + fn0-1 of t0 (12); stage A0(t1)
        #pragma unroll
        for (int m = 0; m < 4; ++m) { fA[m][0] = rdA(t0, m, 0); fA[m][1] = rdA(t0, m, 1); }
        #pragma unroll
        for (int n = 0; n < 2; ++n) { fB[n][0] = rdB(t0, n, 0); fB[n][1] = rdB(t0, n, 1); }
        stage_half(t1, 0);
        BAR(); WAIT_LGKM0();
        MFMA_Q(0, 0);
        BAR();

        // ---- P2: reads fn2-3 of t0 (4); stage A1(t1)
        #pragma unroll
        for (int n = 0; n < 2; ++n) { fB[2 + n][0] = rdB(t0, 2 + n, 0); fB[2 + n][1] = rdB(t0, 2 + n, 1); }
        stage_half(t1, 1);
        BAR(); WAIT_LGKM0();
        MFMA_Q(0, 2);
        BAR();

        // ---- P3: reads fm4-7 of t0 (8); stage B0(t0+2)  [B(t0) last read P2]
        #pragma unroll
        for (int m = 0; m < 4; ++m) { fA[m][0] = rdA(t0, 4 + m, 0); fA[m][1] = rdA(t0, 4 + m, 1); }
        if (more) stage_half(t0 + 2, 2);
        BAR(); WAIT_LGKM0();
        MFMA_Q(4, 2);
        BAR();

        // ---- P4: no reads; stage B1(t0+2); vmcnt(4) -> t1 fully landed
        if (more) {
            stage_half(t0 + 2, 3);
            asm volatile("s_waitcnt vmcnt(4)" ::: "memory");
        } else {
            asm volatile("s_waitcnt vmcnt(0)" ::: "memory");
        }
        BAR();
        MFMA_Q(4, 0);
        BAR();

        // ---- P5: reads fm0-3 + fn0-1 of t1 (12); stage A0(t0+2)  [A(t0) last read P3]
        #pragma unroll
        for (int m = 0; m < 4; ++m) { fA[m][0] = rdA(t1, m, 0); fA[m][1] = rdA(t1, m, 1); }
        #pragma unroll
        for (int n = 0; n < 2; ++n) { fB[n][0] = rdB(t1, n, 0); fB[n][1] = rdB(t1, n, 1); }
        if (more) stage_half(t0 + 2, 0);
        BAR(); WAIT_LGKM0();
        MFMA_Q(0, 0);
        BAR();

        // ---- P6: reads fn2-3 of t1 (4); stage A1(t0+2)
        #pragma unroll
        for (int n = 0; n < 2; ++n) { fB[2 + n][0] = rdB(t1, 2 + n, 0); fB[2 + n][1] = rdB(t1, 2 + n, 1); }
        if (more) stage_half(t0 + 2, 1);
        BAR(); WAIT_LGKM0();
        MFMA_Q(0, 2);
        BAR();

        // ---- P7: reads fm4-7 of t1 (8); stage B0(t1+2)  [B(t1) last read P6]
        #pragma unroll
        for (int m = 0; m < 4; ++m) { fA[m][0] = rdA(t1, 4 + m, 0); fA[m][1] = rdA(t1, 4 + m, 1); }
        if (more) stage_half(t1 + 2, 2);
        BAR(); WAIT_LGKM0();
        MFMA_Q(4, 2);
        BAR();

        // ---- P8: no reads; stage B1(t1+2); vmcnt(4) -> t0+2 fully landed
        if (more) {
            stage_half(t1 + 2, 3);
            asm volatile("s_waitcnt vmcnt(4)" ::: "memory");
        } else {
            asm volatile("s_waitcnt vmcnt(0)" ::: "memory");
        }
        BAR();
        MFMA_Q(4, 0);
        BAR();
    }
    #undef MFMA_Q

    const int which = n0 >> 10;           // 256-wide N-tile lies in one of q/k/v
    const int nb = n0 & 1023;
    if (which < 2) {
        const float* bias = which ? bk : bq;
        unsigned short* outp = which ? ko : qo;
        // q: fold softmax scale AND log2e for native v_exp_f32 (2^x) in attn
        const float sc = which ? 1.f : 0.125f * 1.44269504088896f;
        #pragma unroll
        for (int fm = 0; fm < 8; ++fm)
            #pragma unroll
            for (int fn = 0; fn < 4; ++fn) {
                int colg = nb + wc * 64 + fn * 16 + l15;
                int h = colg >> 6, d = colg & 63;
                float bi = bias[colg];
                #pragma unroll
                for (int r = 0; r < 4; ++r) {
                    int row = m0 + wr * 128 + fm * 16 + quad * 4 + r;
                    int b = row >> 11, t = row & 2047;
                    outp[(((size_t)b * 16 + h) * 2048 + t) * 64 + d] = f2bf((acc[fm][fn][r] + bi) * sc);
                }
            }
    } else {
        // V: transpose via LDS, 4 sub-blocks of 128(m) x 128(n), padded stride 136
        const int b = m0 >> 11;
        for (int mh = 0; mh < 2; ++mh)
            for (int nh = 0; nh < 2; ++nh) {
                __syncthreads();
                if (wr == mh && (wc >> 1) == nh) {
                    const int cc = wc & 1;
                    #pragma unroll
                    for (int fm = 0; fm < 8; ++fm)
                        #pragma unroll
                        for (int fn = 0; fn < 4; ++fn) {
                            int colL = cc * 64 + fn * 16 + l15;          // 0..127
                            int colg = nb + nh * 128 + colL;
                            float bi = bv[colg];
                            u16x4 pk;
                            #pragma unroll
                            for (int r = 0; r < 4; ++r) pk[r] = f2bf(acc[fm][fn][r] + bi);
                            *(u16x4*)&sm[colL * 136 + fm * 16 + quad * 4] = pk;
                        }
                }
                __syncthreads();
                const int nl = tid >> 2, tq = tid & 3;                   // col 0..127, quarter
                const int colg = nb + nh * 128 + nl;
                const int h = colg >> 6, d = colg & 63;
                const int t0 = (m0 & 2047) + mh * 128;
                unsigned short* dst = vt + (((size_t)b * 16 + h) * 64 + d) * 2048 + t0 + tq * 32;
                #pragma unroll
                for (int j = 0; j < 4; ++j)
                    *(float4*)&dst[j * 8] = *(const float4*)&sm[nl * 136 + tq * 32 + j * 8];
            }
    }
}

// ---------------------------------------------------------------------------
// Flash attention v4: 128 q/block (4 waves, wave = 32q x all keys),
// KVBLK=128 (17 trips via leg-pairing p/15-p), GLD double-buffered staging,
// 1 vmcnt(0)+barrier per trip. In-register P with v_permlane32_swap exchange
// (VALU pipe - no lgkmcnt serialization). Native v_exp_f32 (q pre-scaled by
// 0.125*log2e in qkv). 4 independent S chains/trip; split O accumulators.
// K: [128][64] 3-bit XOR swizzle; V^T: [64][128] 4-bit XOR swizzle.
// grid (64 bh, 8 pairs), block 256. LDS 64KB -> 2 blocks/CU.
// C/D layout (verified): col=lane&31, row=(reg&3)+8*(reg>>2)+4*(lane>>5).
// ---------------------------------------------------------------------------
__global__ __launch_bounds__(256, 2) void attn_kernel(
    const unsigned short* __restrict__ q, const unsigned short* __restrict__ k,
    const unsigned short* __restrict__ vt, unsigned short* __restrict__ att2)
{
    __shared__ __align__(16) unsigned short KV[2][2][8192];   // [buf][K|V]

    const int tid = threadIdx.x;
    const int w = tid >> 6, lane = tid & 63;
    const int l31 = lane & 31, h = lane >> 5;
    const int bh = blockIdx.x;
    const int rs = l31 & 7, rv = l31 & 15;

    const unsigned short* kb = k  + (size_t)bh * 2048 * 64;
    const unsigned short* vb = vt + (size_t)bh * 64 * 2048;

    // K staging: wave w rows 32w+8r+(lane>>3), slot lane&7 <- chunk (lane&7)^(row&7)
    const size_t kOff = (size_t)(32 * w + (lane >> 3)) * 64 + (size_t)(((lane & 7) ^ (lane >> 3)) * 8);
    // V staging: wave w d-rows 16w+4r+(lane>>4), slot lane&15 <- chunk slot^(d&15)
    const int vRow = lane >> 4, vc = lane & 15;
    size_t vOff[4];
    #pragma unroll
    for (int r = 0; r < 4; ++r)
        vOff[r] = (size_t)(16 * w + 4 * r + vRow) * 2048
                + (size_t)((vc ^ ((4 * r + vRow) & 15)) * 8);

    auto stage = [&](int jt, int buf) {
        unsigned short* dK = &KV[buf][0][w * 2048];
        unsigned short* dV = &KV[buf][1][w * 2048];
        const unsigned short* sK = kb + kOff + (size_t)jt * 8192;
        #pragma unroll
        for (int r = 0; r < 4; ++r) GLD(sK + r * 512, dK + r * 512);
        #pragma unroll
        for (int r = 0; r < 4; ++r) GLD(vb + vOff[r] + jt * 128, dV + r * 512);
    };

    for (int leg = 0; leg < 2; ++leg) {
        const int qtile = leg ? (15 - (int)blockIdx.y) : (int)blockIdx.y;
        const int qb0 = qtile * 128;
        const int qmin = qb0 + w * 32, qmax = qmin + 31;
        const int qg = qmin + l31;             // query owned as S^T COLUMN
        const int trips = qtile + 1;           // 128-key tiles

        // Q B-fragments straight from global: B[k=d][n=query]
        bf16x8 fQ[4];
        {
            const unsigned short* qp = q + ((size_t)bh * 2048 + qg) * 64 + h * 8;
            #pragma unroll
            for (int ks = 0; ks < 4; ++ks) fQ[ks] = *(const bf16x8*)&qp[ks * 16];
        }

        f32x16 Oa[2], Ob[2];
        #pragma unroll
        for (int nt = 0; nt < 2; ++nt)
            #pragma unroll
            for (int i = 0; i < 16; ++i) { Oa[nt][i] = 0.f; Ob[nt][i] = 0.f; }
        float lsum = 0.f;

        stage(0, 0);
        asm volatile("s_waitcnt vmcnt(0)" ::: "memory");
        BAR();

        for (int jt = 0; jt < trips; ++jt) {
            const int buf = jt & 1;
            if (jt + 1 < trips) stage(jt + 1, buf ^ 1);
            const unsigned short* Ks = KV[buf][0];
            const unsigned short* Vs = KV[buf][1];
            const int key0 = jt * 128;

            // QK^T: 4 independent 32-key subtile chains
            f32x16 S[4];
            #pragma unroll
            for (int kt = 0; kt < 4; ++kt)
                #pragma unroll
                for (int i = 0; i < 16; ++i) S[kt][i] = 0.f;
            __builtin_amdgcn_s_setprio(1);
            #pragma unroll
            for (int kt = 0; kt < 4; ++kt) {
                if (key0 + 32 * kt <= qmax) {
                    const int row = kt * 32 + l31;
                    #pragma unroll
                    for (int ks = 0; ks < 4; ++ks) {
                        bf16x8 aK = *(const bf16x8*)&Ks[row * 64 + (((2 * ks + h) ^ rs) * 8)];
                        S[kt] = __builtin_amdgcn_mfma_f32_32x32x16_bf16(aK, fQ[ks], S[kt], 0, 0, 0);
                    }
                }
            }
            __builtin_amdgcn_s_setprio(0);

            // per subtile: softmax (native 2^x) -> in-reg P (permlane swap) -> PV
            #pragma unroll
            for (int kt = 0; kt < 4; ++kt) {
                if (key0 + 32 * kt <= qmax) {
                    const bool nm = (key0 + 32 * kt + 31) > qmin;
                    unsigned int e0[4], e1[4];
                    float lst = 0.f;
                    #pragma unroll
                    for (int g = 0; g < 4; ++g) {
                        float p[4];
                        #pragma unroll
                        for (int r = 0; r < 4; ++r) {
                            float pv = ex2(S[kt][4 * g + r]);
                            if (nm) {
                                int key = key0 + kt * 32 + 8 * g + 4 * h + r;
                                if (key > qg) pv = 0.f;
                            }
                            p[r] = pv;
                        }
                        lst += (p[0] + p[1]) + (p[2] + p[3]);
                        e0[g] = pk2(p[0], p[1]);
                        e1[g] = pk2(p[2], p[3]);
                    }
                    lsum += lst;

                    __builtin_amdgcn_s_setprio(1);
                    #pragma unroll
                    for (int s = 0; s < 2; ++s) {
                        // one swap fills two fragment words (keys 16s+8h+{0..7})
                        unsigned int a = e0[2 * s], b = e0[2 * s + 1];
                        pl32swap(a, b);                       // a={keys+0,+1}, b={+4,+5}
                        unsigned int c2 = e1[2 * s], d2 = e1[2 * s + 1];
                        pl32swap(c2, d2);                     // c2={+2,+3}, d2={+6,+7}
                        u32x4 t; t[0] = a; t[1] = c2; t[2] = b; t[3] = d2;
                        bf16x8 aP = __builtin_bit_cast(bf16x8, t);
                        const int cb = 4 * kt + 2 * s;        // V chunk c = cb + h
                        #pragma unroll
                        for (int nt = 0; nt < 2; ++nt) {
                            const int drow = nt * 32 + l31;
                            bf16x8 bV = *(const bf16x8*)&Vs[drow * 128 + (((cb + h) ^ rv) * 8)];
                            if (kt & 1)
                                Ob[nt] = __builtin_amdgcn_mfma_f32_32x32x16_bf16(aP, bV, Ob[nt], 0, 0, 0);
                            else
                                Oa[nt] = __builtin_amdgcn_mfma_f32_32x32x16_bf16(aP, bV, Oa[nt], 0, 0, 0);
                        }
                    }
                    __builtin_amdgcn_s_setprio(0);
                }
            }

            asm volatile("s_waitcnt vmcnt(0)" ::: "memory");   // next tile landed
            BAR();
        }

        // lsum split across half-waves (query qg in lanes l31 and l31+32)
        lsum += __shfl_xor(lsum, 32);
        const float inv = 1.f / lsum;

        // O[nt][4g+r]: query row 8g+4h+r, d col nt*32+l31 (C/D layout)
        unsigned short* ob = att2 + ((size_t)bh * 2048 + qmin) * 64;
        #pragma unroll
        for (int g = 0; g < 4; ++g)
            #pragma unroll
            for (int r = 0; r < 4; ++r) {
                const int qy = 8 * g + 4 * h + r;
                const float iv = __shfl(inv, qy);
                #pragma unroll
                for (int nt = 0; nt < 2; ++nt)
                    ob[(size_t)qy * 64 + nt * 32 + l31] =
                        f2bf((Oa[nt][4 * g + r] + Ob[nt][4 * g + r]) * iv);
            }
    }
}

// ---------------------------------------------------------------------------
// Output projection: A in [b][h][t][64] layout, Wp^T [n][e], fp32 out + bias.
// 128x128 tiles, global_load_lds. grid (64, 8), block 256.
// ---------------------------------------------------------------------------
__global__ __launch_bounds__(256) void proj_gemm(
    const unsigned short* __restrict__ A,    // att2 bf16 [b*16+h][t][64]
    const unsigned short* __restrict__ wpt,
    const float* __restrict__ bp,
    float* __restrict__ out)
{
    __shared__ __align__(16) unsigned short sm[16384];
    unsigned short* As = sm;
    unsigned short* Bs = sm + 8192;

    const int tid = threadIdx.x;
    const int w = tid >> 6, lane = tid & 63, l15 = lane & 15, quad = lane >> 4;
    const int m0 = blockIdx.x * 128;
    const int n0 = blockIdx.y * 128;

    f32x4 acc[2][8];
    #pragma unroll
    for (int s = 0; s < 2; ++s)
        #pragma unroll
        for (int n = 0; n < 8; ++n) acc[s][n] = (f32x4){0.f, 0.f, 0.f, 0.f};

    // A element (m,k) at A[((m>>11)*16 + (k>>6))*131072 + (m&2047)*64 + (k&63)]
    const unsigned short* Ag = A + (size_t)(m0 >> 11) * 16 * 131072
                                 + (size_t)((m0 & 2047) + 32 * w + (lane >> 3)) * 64 + (lane & 7) * 8;
    const unsigned short* Bg = wpt + (size_t)(n0 + 32 * w + (lane >> 3)) * 1024 + (lane & 7) * 8;
    unsigned short* Al = As + (32 * w) * 64;
    unsigned short* Bl = Bs + (32 * w) * 64;

    for (int k0 = 0; k0 < 1024; k0 += 64) {
        __syncthreads();
        const size_t aoff = (size_t)(k0 >> 6) * 131072;
        #pragma unroll
        for (int j = 0; j < 4; ++j) {
            GLD(Ag + aoff + (size_t)(8 * j) * 64, Al + (8 * j) * 64);
            GLD(Bg + (size_t)(8 * j) * 1024 + k0, Bl + (8 * j) * 64);
        }
        __syncthreads();
        #pragma unroll
        for (int ks = 0; ks < 2; ++ks) {
            bf16x8 a0 = *(const bf16x8*)&As[(32 * w + l15) * 64 + ks * 32 + quad * 8];
            bf16x8 a1 = *(const bf16x8*)&As[(32 * w + 16 + l15) * 64 + ks * 32 + quad * 8];
            #pragma unroll
            for (int n = 0; n < 8; ++n) {
                bf16x8 b = *(const bf16x8*)&Bs[(16 * n + l15) * 64 + ks * 32 + quad * 8];
                acc[0][n] = __builtin_amdgcn_mfma_f32_16x16x32_bf16(a0, b, acc[0][n], 0, 0, 0);
                acc[1][n] = __builtin_amdgcn_mfma_f32_16x16x32_bf16(a1, b, acc[1][n], 0, 0, 0);
            }
        }
    }

    #pragma unroll
    for (int s = 0; s < 2; ++s)
        #pragma unroll
        for (int n = 0; n < 8; ++n) {
            float bi = bp[n0 + 16 * n + l15];
            #pragma unroll
            for (int r = 0; r < 4; ++r) {
                int row = m0 + 32 * w + 16 * s + quad * 4 + r;
                out[(size_t)row * 1024 + n0 + 16 * n + l15] = acc[s][n][r] + bi;
            }
        }
}

extern "C" void kernel_launch(void* const* d_in, const int* in_sizes, int n_in,
                              void* d_out, int out_size, void* d_ws, size_t ws_size,
                              hipStream_t stream) {
    const float* x  = (const float*)d_in[0];
    const float* Wq = (const float*)d_in[1];
    const float* Wk = (const float*)d_in[2];
    const float* Wv = (const float*)d_in[3];
    const float* bq = (const float*)d_in[4];
    const float* bk = (const float*)d_in[5];
    const float* bv = (const float*)d_in[6];
    const float* Wp = (const float*)d_in[7];
    const float* bp = (const float*)d_in[8];
    float* out = (float*)d_out;

    const size_t nx = (size_t)B_ * T_ * E_;
    unsigned short* base = (unsigned short*)d_ws;
    unsigned short* xb  = base;
    unsigned short* qb  = xb + nx;
    unsigned short* kb  = qb + nx;
    unsigned short* vtb = kb + nx;
    unsigned short* atb = vtb + nx;          // [bh][t][64]
    unsigned short* wf  = atb + nx;          // [3072][1024]
    unsigned short* wpt = wf + 3072 * 1024;  // [1024][1024]

    cast_x_kernel<<<(int)(nx / 4 + 255) / 256, 256, 0, stream>>>(x, xb, (int)(nx / 4));
    tcast_all<<<dim3(16, 64), 256, 0, stream>>>(Wq, Wk, Wv, Wp, wf, wpt);
    qkv_gemm<<<dim3(32, 12), 512, 0, stream>>>(xb, wf, bq, bk, bv, qb, kb, vtb);
    attn_kernel<<<dim3(64, 8), 256, 0, stream>>>(qb, kb, vtb, atb);
    proj_gemm<<<dim3(64, 8), 256, 0, stream>>>(atb, wpt, bp, out);
}

// Round 8
// 265.622 us; speedup vs baseline: 1.0460x; 1.0150x over previous
//
#include <hip/hip_runtime.h>
#include <math.h>

#define B_ 4
#define T_ 2048
#define E_ 1024
#define H_ 16
#define D_ 64

typedef __bf16 bf16_t;
typedef bf16_t bf16x8 __attribute__((ext_vector_type(8)));
typedef float  f32x4  __attribute__((ext_vector_type(4)));
typedef float  f32x16 __attribute__((ext_vector_type(16)));
typedef unsigned short u16x4 __attribute__((ext_vector_type(4)));
typedef unsigned int   u32x4 __attribute__((ext_vector_type(4)));

static __device__ __forceinline__ unsigned short f2bf(float f) {
    bf16_t h = (bf16_t)f;
    return __builtin_bit_cast(unsigned short, h);
}
static __device__ __forceinline__ unsigned int pk2(float a, float b) {
    return (unsigned int)f2bf(a) | ((unsigned int)f2bf(b) << 16);
}
// native 2^x (q is pre-scaled by 0.125*log2e so this computes e^(orig S))
static __device__ __forceinline__ float ex2(float x) {
    float r; asm("v_exp_f32 %0, %1" : "=v"(r) : "v"(x)); return r;
}
// v_permlane32_swap_b32: a' = {a.row0, b.row0}, b' = {a.row1, b.row1}
static __device__ __forceinline__ void pl32swap(unsigned int& a, unsigned int& b) {
    asm("v_permlane32_swap_b32 %0, %1" : "+v"(a), "+v"(b));
}

// async global->LDS, 16B per lane; lds base wave-uniform + lane*16
#define GLD(gp, lp) __builtin_amdgcn_global_load_lds( \
    (const __attribute__((address_space(1))) unsigned int*)(gp), \
    (__attribute__((address_space(3))) unsigned int*)(lp), 16, 0, 0)

#define BAR() __builtin_amdgcn_s_barrier()
#define WAIT_LGKM0() asm volatile("s_waitcnt lgkmcnt(0)" ::: "memory")
#define VMC(n) asm volatile("s_waitcnt vmcnt(" #n ")" ::: "memory")

// ---------------------------------------------------------------------------
// x fp32 -> bf16
// ---------------------------------------------------------------------------
__global__ void cast_x_kernel(const float* __restrict__ in, unsigned short* __restrict__ out, int n4) {
    int i = blockIdx.x * blockDim.x + threadIdx.x;
    if (i >= n4) return;
    float4 v = ((const float4*)in)[i];
    ushort4 o;
    o.x = f2bf(v.x); o.y = f2bf(v.y); o.z = f2bf(v.z); o.w = f2bf(v.w);
    ((ushort4*)out)[i] = o;
}

// ---------------------------------------------------------------------------
// fused transpose-cast for all 4 weights. grid (16, 64), block 256.
// grp 0..2: Wq/Wk/Wv [h][e][d] -> wf[(grp*1024+h*64+d)][e]; grp 3: Wp [e][n] -> wpt[n][e]
// ---------------------------------------------------------------------------
__global__ void tcast_all(const float* __restrict__ Wq, const float* __restrict__ Wk,
                          const float* __restrict__ Wv, const float* __restrict__ Wp,
                          unsigned short* __restrict__ wf, unsigned short* __restrict__ wpt) {
    __shared__ unsigned short Ts[64 * 66];
    const int grp = blockIdx.y >> 4, yy = blockIdx.y & 15;
    const float* in; unsigned short* out; int yA, S;
    if (grp == 3) { in = Wp; out = wpt; yA = 64;    S = 1024; }
    else {
        in = (grp == 0) ? Wq : (grp == 1) ? Wk : Wv;
        out = wf + (size_t)grp * 1024 * 1024; yA = 65536; S = 64;
    }
    const int tid = threadIdx.x;
    const int r = tid >> 2, c4 = tid & 3;
    const float* ip = in + (size_t)yA * yy + (size_t)(blockIdx.x * 64 + r) * S + c4 * 16;
    #pragma unroll
    for (int j = 0; j < 4; ++j) {
        float4 v = *(const float4*)&ip[j * 4];
        Ts[(c4 * 16 + j * 4 + 0) * 66 + r] = f2bf(v.x);
        Ts[(c4 * 16 + j * 4 + 1) * 66 + r] = f2bf(v.y);
        Ts[(c4 * 16 + j * 4 + 2) * 66 + r] = f2bf(v.z);
        Ts[(c4 * 16 + j * 4 + 3) * 66 + r] = f2bf(v.w);
    }
    __syncthreads();
    unsigned short* op = out + (size_t)(yy * 64 + r) * 1024 + blockIdx.x * 64 + c4 * 16;
    #pragma unroll
    for (int j = 0; j < 4; ++j) {
        u16x4 pk;
        #pragma unroll
        for (int m = 0; m < 4; ++m) pk[m] = Ts[r * 66 + c4 * 16 + j * 4 + m];
        *(u16x4*)&op[j * 4] = pk;
    }
}

// ---------------------------------------------------------------------------
// 128x256-tile 8-wave GEMM core (qkv + proj): 512 thr (2Mx4N waves, 64x64
// per wave, acc[4][4]), BK=64, 2 phases/K-tile (P-lo: read A+Blo, 16 MFMA;
// P-hi: read Bhi, 16 MFMA), 2 K-tiles per iteration = 4 phases.
// LDS 96KB: per buffer A[128][64] @0, B[256][64] @8192 (u16). 1 block/CU.
// T2 swizzle: linear GLD dest + inverse-swizzled global source (rule 21).
// BLOCK-WIDE read map per tile t: A last read @ its P-lo, Blo @ P-lo,
// Bhi @ P-hi. STAGING LEDGER (>=1 barrier after last reader, 3-phase
// issue->read gaps; vmcnt(6) at every phase end forces exactly the loads
// read 2 phases later — outstanding sets enumerated in session journal):
//   P1: Bh(t1) | P2: A(t0+2), Bl(t0+2) | P3: Bh(t0+2) | P4: A(t1+2), Bl(t1+2)
// Tail (last iter): vmcnt(2) end-P2, vmcnt(0) end-P3.
// qkv grid 768 = 3 full CU rounds (was 1.5 work-rounds over 2 -> 25% idle);
// proj grid 256 = 1 round. XCD-chunked bijective swizzle (grid%8==0).
// ---------------------------------------------------------------------------

#define GEMM_CORE_DECLS \
    const int tid = threadIdx.x; \
    const int w = tid >> 6, lane = tid & 63; \
    const int wr = w >> 2, wc = w & 3; \
    const int l15 = lane & 15, quad = lane >> 4, lsw = l15 & 7; \
    const int rowg = lane >> 3; \
    const int swz = ((lane & 7) ^ rowg) * 8; \
    f32x4 acc[4][4]; \
    _Pragma("unroll") for (int i_ = 0; i_ < 4; ++i_) \
        _Pragma("unroll") for (int j_ = 0; j_ < 4; ++j_) \
            acc[i_][j_] = (f32x4){0.f, 0.f, 0.f, 0.f};

#define MFMA_P(nb) \
    __builtin_amdgcn_s_setprio(1); \
    _Pragma("unroll") for (int m_ = 0; m_ < 4; ++m_) \
        _Pragma("unroll") for (int j_ = 0; j_ < 2; ++j_) \
            _Pragma("unroll") for (int k_ = 0; k_ < 2; ++k_) \
                acc[m_][(nb) + j_] = __builtin_amdgcn_mfma_f32_16x16x32_bf16( \
                    fA[m_][k_], fB[(nb) + j_][k_], acc[m_][(nb) + j_], 0, 0, 0); \
    __builtin_amdgcn_s_setprio(0);

// 8 iterations (16 K-tiles), stageA/stageB/rdA/rdB provided as lambdas
#define GEMM_K_LOOP \
    stageA(0, 0); stageA(0, 1); stageB(0, 0, 0); stageB(0, 0, 1); \
    stageB(0, 1, 0); stageB(0, 1, 1); \
    stageA(1, 0); stageA(1, 1); stageB(1, 0, 0); stageB(1, 0, 1); \
    VMC(6); BAR(); \
    _Pragma("unroll 1") \
    for (int it = 0; it < 8; ++it) { \
        const int t0 = 2 * it, t1 = 2 * it + 1; \
        const bool more = it < 7; \
        bf16x8 fA[4][2], fB[4][2]; \
        /* P1: reads fA(t0)+fBlo(t0); stage Bh(t1) */ \
        _Pragma("unroll") for (int m_ = 0; m_ < 4; ++m_) { fA[m_][0] = rdA(t0, m_, 0); fA[m_][1] = rdA(t0, m_, 1); } \
        _Pragma("unroll") for (int n_ = 0; n_ < 2; ++n_) { fB[n_][0] = rdB(t0, n_, 0); fB[n_][1] = rdB(t0, n_, 1); } \
        stageB(t1, 1, 0); stageB(t1, 1, 1); \
        BAR(); WAIT_LGKM0(); \
        MFMA_P(0); \
        VMC(6); BAR(); \
        /* P2: reads fBhi(t0); stage A(t0+2), Bl(t0+2) */ \
        _Pragma("unroll") for (int n_ = 0; n_ < 2; ++n_) { fB[2 + n_][0] = rdB(t0, 2 + n_, 0); fB[2 + n_][1] = rdB(t0, 2 + n_, 1); } \
        if (more) { stageA(t0 + 2, 0); stageA(t0 + 2, 1); stageB(t0 + 2, 0, 0); stageB(t0 + 2, 0, 1); } \
        BAR(); WAIT_LGKM0(); \
        MFMA_P(2); \
        if (more) { VMC(6); } else { VMC(2); } \
        BAR(); \
        /* P3: reads fA(t1)+fBlo(t1); stage Bh(t0+2) */ \
        _Pragma("unroll") for (int m_ = 0; m_ < 4; ++m_) { fA[m_][0] = rdA(t1, m_, 0); fA[m_][1] = rdA(t1, m_, 1); } \
        _Pragma("unroll") for (int n_ = 0; n_ < 2; ++n_) { fB[n_][0] = rdB(t1, n_, 0); fB[n_][1] = rdB(t1, n_, 1); } \
        if (more) { stageB(t0 + 2, 1, 0); stageB(t0 + 2, 1, 1); } \
        BAR(); WAIT_LGKM0(); \
        MFMA_P(0); \
        if (more) { VMC(6); } else { VMC(0); } \
        BAR(); \
        /* P4: reads fBhi(t1); stage A(t1+2), Bl(t1+2) */ \
        _Pragma("unroll") for (int n_ = 0; n_ < 2; ++n_) { fB[2 + n_][0] = rdB(t1, 2 + n_, 0); fB[2 + n_][1] = rdB(t1, 2 + n_, 1); } \
        if (more) { stageA(t1 + 2, 0); stageA(t1 + 2, 1); stageB(t1 + 2, 0, 0); stageB(t1 + 2, 0, 1); } \
        BAR(); WAIT_LGKM0(); \
        MFMA_P(2); \
        if (more) { VMC(6); } \
        BAR(); \
    }

// ---------------------------------------------------------------------------
// Fused QKV GEMM: [8192 x 1024] x [3072 x 1024]^T, 128x256 tiles.
// q scaled 0.125*log2e (+bias); k +bias; v (+bias) transposed [bh][64][T].
// grid 768 (1D), block 512.
// ---------------------------------------------------------------------------
__global__ __launch_bounds__(512, 2) void qkv_gemm(
    const unsigned short* __restrict__ xb,
    const unsigned short* __restrict__ wf,
    const float* __restrict__ bq, const float* __restrict__ bk, const float* __restrict__ bv,
    unsigned short* __restrict__ qo, unsigned short* __restrict__ ko,
    unsigned short* __restrict__ vt)
{
    __shared__ __align__(16) unsigned short sm[49152];   // 96 KiB

    // XCD-chunked bijective swizzle: 768 % 8 == 0; same-B-panel blocks per XCD
    const int bid = blockIdx.x;
    const int logical = (bid & 7) * 96 + (bid >> 3);
    const int m0 = (logical & 63) * 128;
    const int n0 = (logical >> 6) * 256;

    GEMM_CORE_DECLS

    auto stageA = [&](int t, int g) {
        const int rb = w * 16 + g * 8;
        unsigned short* dst = sm + (t & 1) * 24576 + rb * 64;
        GLD(xb + (size_t)(m0 + rb + rowg) * 1024 + t * 64 + swz, dst);
    };
    auto stageB = [&](int t, int R, int g) {
        const int rb = w * 16 + g * 8;
        const int ar0 = (rb >> 5) * 64 + R * 32 + (rb & 31);
        unsigned short* dst = sm + (t & 1) * 24576 + 8192 + ar0 * 64;
        GLD(wf + (size_t)(n0 + ar0 + rowg) * 1024 + t * 64 + swz, dst);
    };
    auto rdA = [&](int t, int fm, int ks) {
        const int row = wr * 64 + fm * 16 + l15;
        return *(const bf16x8*)&sm[(t & 1) * 24576 + row * 64 + (((ks * 4 + quad) ^ lsw) * 8)];
    };
    auto rdB = [&](int t, int fn, int ks) {
        const int row = wc * 64 + fn * 16 + l15;
        return *(const bf16x8*)&sm[(t & 1) * 24576 + 8192 + row * 64 + (((ks * 4 + quad) ^ lsw) * 8)];
    };

    GEMM_K_LOOP

    const int which = n0 >> 10;           // q / k / v
    const int nb = n0 & 1023;
    if (which < 2) {
        const float* bias = which ? bk : bq;
        unsigned short* outp = which ? ko : qo;
        // q: fold softmax scale AND log2e for native v_exp_f32 (2^x) in attn
        const float sc = which ? 1.f : 0.125f * 1.44269504088896f;
        #pragma unroll
        for (int fm = 0; fm < 4; ++fm)
            #pragma unroll
            for (int fn = 0; fn < 4; ++fn) {
                int colg = nb + wc * 64 + fn * 16 + l15;
                int h = colg >> 6, d = colg & 63;
                float bi = bias[colg];
                #pragma unroll
                for (int r = 0; r < 4; ++r) {
                    int row = m0 + wr * 64 + fm * 16 + quad * 4 + r;
                    int b = row >> 11, t = row & 2047;
                    outp[(((size_t)b * 16 + h) * 2048 + t) * 64 + d] = f2bf((acc[fm][fn][r] + bi) * sc);
                }
            }
    } else {
        // V: transpose via LDS, 2 sub-blocks of 128(n) x 128(m), stride 136
        const int b = m0 >> 11, t0r = m0 & 2047;
        for (int nh = 0; nh < 2; ++nh) {
            __syncthreads();
            if ((wc >> 1) == nh) {
                const int cc = wc & 1;
                #pragma unroll
                for (int fm = 0; fm < 4; ++fm)
                    #pragma unroll
                    for (int fn = 0; fn < 4; ++fn) {
                        int colL = cc * 64 + fn * 16 + l15;          // 0..127
                        int colg = nb + nh * 128 + colL;
                        float bi = bv[colg];
                        u16x4 pk;
                        #pragma unroll
                        for (int r = 0; r < 4; ++r) pk[r] = f2bf(acc[fm][fn][r] + bi);
                        *(u16x4*)&sm[colL * 136 + wr * 64 + fm * 16 + quad * 4] = pk;
                    }
            }
            __syncthreads();
            const int nl = tid >> 2, tq = tid & 3;                   // col 0..127
            const int colg = nb + nh * 128 + nl;
            const int h = colg >> 6, d = colg & 63;
            unsigned short* dst = vt + (((size_t)b * 16 + h) * 64 + d) * 2048 + t0r + tq * 32;
            #pragma unroll
            for (int j = 0; j < 4; ++j)
                *(float4*)&dst[j * 8] = *(const float4*)&sm[nl * 136 + tq * 32 + j * 8];
        }
    }
}

// ---------------------------------------------------------------------------
// Output projection: A = att2 bf16 [b*16+h][t][64] (gathered), B = Wp^T,
// fp32 out + bias. 128x256 tiles, same core. grid 256 (1D), block 512.
// ---------------------------------------------------------------------------
__global__ __launch_bounds__(512, 2) void proj_gemm(
    const unsigned short* __restrict__ A,
    const unsigned short* __restrict__ wpt,
    const float* __restrict__ bp,
    float* __restrict__ out)
{
    __shared__ __align__(16) unsigned short sm[49152];   // 96 KiB

    const int bid = blockIdx.x;
    const int logical = (bid & 7) * 32 + (bid >> 3);     // 256 % 8 == 0
    const int m0 = (logical & 63) * 128;
    const int n0 = (logical >> 6) * 256;

    GEMM_CORE_DECLS

    // A element (m,k) at A[((m>>11)*16 + (k>>6))*131072 + (m&2047)*64 + (k&63)]
    const unsigned short* Ab = A + (size_t)(m0 >> 11) * 16 * 131072 + (size_t)(m0 & 2047) * 64;
    auto stageA = [&](int t, int g) {
        const int rb = w * 16 + g * 8;
        unsigned short* dst = sm + (t & 1) * 24576 + rb * 64;
        GLD(Ab + (size_t)t * 131072 + (rb + rowg) * 64 + swz, dst);
    };
    auto stageB = [&](int t, int R, int g) {
        const int rb = w * 16 + g * 8;
        const int ar0 = (rb >> 5) * 64 + R * 32 + (rb & 31);
        unsigned short* dst = sm + (t & 1) * 24576 + 8192 + ar0 * 64;
        GLD(wpt + (size_t)(n0 + ar0 + rowg) * 1024 + t * 64 + swz, dst);
    };
    auto rdA = [&](int t, int fm, int ks) {
        const int row = wr * 64 + fm * 16 + l15;
        return *(const bf16x8*)&sm[(t & 1) * 24576 + row * 64 + (((ks * 4 + quad) ^ lsw) * 8)];
    };
    auto rdB = [&](int t, int fn, int ks) {
        const int row = wc * 64 + fn * 16 + l15;
        return *(const bf16x8*)&sm[(t & 1) * 24576 + 8192 + row * 64 + (((ks * 4 + quad) ^ lsw) * 8)];
    };

    GEMM_K_LOOP

    #pragma unroll
    for (int fm = 0; fm < 4; ++fm)
        #pragma unroll
        for (int fn = 0; fn < 4; ++fn) {
            int col = n0 + wc * 64 + fn * 16 + l15;
            float bi = bp[col];
            #pragma unroll
            for (int r = 0; r < 4; ++r) {
                int row = m0 + wr * 64 + fm * 16 + quad * 4 + r;
                out[(size_t)row * 1024 + col] = acc[fm][fn][r] + bi;
            }
        }
}

// ---------------------------------------------------------------------------
// Flash attention v4 (unchanged from round 7): 128 q/block, KVBLK=128,
// GLD double-buffered staging, in-register P via v_permlane32_swap,
// native v_exp_f32 (q pre-scaled 0.125*log2e). grid (64 bh, 8 pairs),
// block 256, LDS 64KB -> 2 blocks/CU.
// C/D layout (verified): col=lane&31, row=(reg&3)+8*(reg>>2)+4*(lane>>5).
// ---------------------------------------------------------------------------
__global__ __launch_bounds__(256, 2) void attn_kernel(
    const unsigned short* __restrict__ q, const unsigned short* __restrict__ k,
    const unsigned short* __restrict__ vt, unsigned short* __restrict__ att2)
{
    __shared__ __align__(16) unsigned short KV[2][2][8192];   // [buf][K|V]

    const int tid = threadIdx.x;
    const int w = tid >> 6, lane = tid & 63;
    const int l31 = lane & 31, h = lane >> 5;
    const int bh = blockIdx.x;
    const int rs = l31 & 7, rv = l31 & 15;

    const unsigned short* kb = k  + (size_t)bh * 2048 * 64;
    const unsigned short* vb = vt + (size_t)bh * 64 * 2048;

    // K staging: wave w rows 32w+8r+(lane>>3), slot lane&7 <- chunk (lane&7)^(row&7)
    const size_t kOff = (size_t)(32 * w + (lane >> 3)) * 64 + (size_t)(((lane & 7) ^ (lane >> 3)) * 8);
    // V staging: wave w d-rows 16w+4r+(lane>>4), slot lane&15 <- chunk slot^(d&15)
    const int vRow = lane >> 4, vc = lane & 15;
    size_t vOff[4];
    #pragma unroll
    for (int r = 0; r < 4; ++r)
        vOff[r] = (size_t)(16 * w + 4 * r + vRow) * 2048
                + (size_t)((vc ^ ((4 * r + vRow) & 15)) * 8);

    auto stage = [&](int jt, int buf) {
        unsigned short* dK = &KV[buf][0][w * 2048];
        unsigned short* dV = &KV[buf][1][w * 2048];
        const unsigned short* sK = kb + kOff + (size_t)jt * 8192;
        #pragma unroll
        for (int r = 0; r < 4; ++r) GLD(sK + r * 512, dK + r * 512);
        #pragma unroll
        for (int r = 0; r < 4; ++r) GLD(vb + vOff[r] + jt * 128, dV + r * 512);
    };

    for (int leg = 0; leg < 2; ++leg) {
        const int qtile = leg ? (15 - (int)blockIdx.y) : (int)blockIdx.y;
        const int qb0 = qtile * 128;
        const int qmin = qb0 + w * 32, qmax = qmin + 31;
        const int qg = qmin + l31;             // query owned as S^T COLUMN
        const int trips = qtile + 1;           // 128-key tiles

        // Q B-fragments straight from global: B[k=d][n=query]
        bf16x8 fQ[4];
        {
            const unsigned short* qp = q + ((size_t)bh * 2048 + qg) * 64 + h * 8;
            #pragma unroll
            for (int ks = 0; ks < 4; ++ks) fQ[ks] = *(const bf16x8*)&qp[ks * 16];
        }

        f32x16 Oa[2], Ob[2];
        #pragma unroll
        for (int nt = 0; nt < 2; ++nt)
            #pragma unroll
            for (int i = 0; i < 16; ++i) { Oa[nt][i] = 0.f; Ob[nt][i] = 0.f; }
        float lsum = 0.f;

        stage(0, 0);
        VMC(0);
        BAR();

        for (int jt = 0; jt < trips; ++jt) {
            const int buf = jt & 1;
            if (jt + 1 < trips) stage(jt + 1, buf ^ 1);
            const unsigned short* Ks = KV[buf][0];
            const unsigned short* Vs = KV[buf][1];
            const int key0 = jt * 128;

            // QK^T: 4 independent 32-key subtile chains
            f32x16 S[4];
            #pragma unroll
            for (int kt = 0; kt < 4; ++kt)
                #pragma unroll
                for (int i = 0; i < 16; ++i) S[kt][i] = 0.f;
            __builtin_amdgcn_s_setprio(1);
            #pragma unroll
            for (int kt = 0; kt < 4; ++kt) {
                if (key0 + 32 * kt <= qmax) {
                    const int row = kt * 32 + l31;
                    #pragma unroll
                    for (int ks = 0; ks < 4; ++ks) {
                        bf16x8 aK = *(const bf16x8*)&Ks[row * 64 + (((2 * ks + h) ^ rs) * 8)];
                        S[kt] = __builtin_amdgcn_mfma_f32_32x32x16_bf16(aK, fQ[ks], S[kt], 0, 0, 0);
                    }
                }
            }
            __builtin_amdgcn_s_setprio(0);

            // per subtile: softmax (native 2^x) -> in-reg P (permlane swap) -> PV
            #pragma unroll
            for (int kt = 0; kt < 4; ++kt) {
                if (key0 + 32 * kt <= qmax) {
                    const bool nm = (key0 + 32 * kt + 31) > qmin;
                    unsigned int e0[4], e1[4];
                    float lst = 0.f;
                    #pragma unroll
                    for (int g = 0; g < 4; ++g) {
                        float p[4];
                        #pragma unroll
                        for (int r = 0; r < 4; ++r) {
                            float pv = ex2(S[kt][4 * g + r]);
                            if (nm) {
                                int key = key0 + kt * 32 + 8 * g + 4 * h + r;
                                if (key > qg) pv = 0.f;
                            }
                            p[r] = pv;
                        }
                        lst += (p[0] + p[1]) + (p[2] + p[3]);
                        e0[g] = pk2(p[0], p[1]);
                        e1[g] = pk2(p[2], p[3]);
                    }
                    lsum += lst;

                    __builtin_amdgcn_s_setprio(1);
                    #pragma unroll
                    for (int s = 0; s < 2; ++s) {
                        unsigned int a = e0[2 * s], b = e0[2 * s + 1];
                        pl32swap(a, b);                       // a={keys+0,+1}, b={+4,+5}
                        unsigned int c2 = e1[2 * s], d2 = e1[2 * s + 1];
                        pl32swap(c2, d2);                     // c2={+2,+3}, d2={+6,+7}
                        u32x4 t; t[0] = a; t[1] = c2; t[2] = b; t[3] = d2;
                        bf16x8 aP = __builtin_bit_cast(bf16x8, t);
                        const int cb = 4 * kt + 2 * s;        // V chunk c = cb + h
                        #pragma unroll
                        for (int nt = 0; nt < 2; ++nt) {
                            const int drow = nt * 32 + l31;
                            bf16x8 bV = *(const bf16x8*)&Vs[drow * 128 + (((cb + h) ^ rv) * 8)];
                            if (kt & 1)
                                Ob[nt] = __builtin_amdgcn_mfma_f32_32x32x16_bf16(aP, bV, Ob[nt], 0, 0, 0);
                            else
                                Oa[nt] = __builtin_amdgcn_mfma_f32_32x32x16_bf16(aP, bV, Oa[nt], 0, 0, 0);
                        }
                    }
                    __builtin_amdgcn_s_setprio(0);
                }
            }

            VMC(0);   // next tile landed
            BAR();
        }

        // lsum split across half-waves (query qg in lanes l31 and l31+32)
        lsum += __shfl_xor(lsum, 32);
        const float inv = 1.f / lsum;

        // O[nt][4g+r]: query row 8g+4h+r, d col nt*32+l31 (C/D layout)
        unsigned short* ob = att2 + ((size_t)bh * 2048 + qmin) * 64;
        #pragma unroll
        for (int g = 0; g < 4; ++g)
            #pragma unroll
            for (int r = 0; r < 4; ++r) {
                const int qy = 8 * g + 4 * h + r;
                const float iv = __shfl(inv, qy);
                #pragma unroll
                for (int nt = 0; nt < 2; ++nt)
                    ob[(size_t)qy * 64 + nt * 32 + l31] =
                        f2bf((Oa[nt][4 * g + r] + Ob[nt][4 * g + r]) * iv);
            }
    }
}

extern "C" void kernel_launch(void* const* d_in, const int* in_sizes, int n_in,
                              void* d_out, int out_size, void* d_ws, size_t ws_size,
                              hipStream_t stream) {
    const float* x  = (const float*)d_in[0];
    const float* Wq = (const float*)d_in[1];
    const float* Wk = (const float*)d_in[2];
    const float* Wv = (const float*)d_in[3];
    const float* bq = (const float*)d_in[4];
    const float* bk = (const float*)d_in[5];
    const float* bv = (const float*)d_in[6];
    const float* Wp = (const float*)d_in[7];
    const float* bp = (const float*)d_in[8];
    float* out = (float*)d_out;

    const size_t nx = (size_t)B_ * T_ * E_;
    unsigned short* base = (unsigned short*)d_ws;
    unsigned short* xb  = base;
    unsigned short* qb  = xb + nx;
    unsigned short* kb  = qb + nx;
    unsigned short* vtb = kb + nx;
    unsigned short* atb = vtb + nx;          // [bh][t][64]
    unsigned short* wf  = atb + nx;          // [3072][1024]
    unsigned short* wpt = wf + 3072 * 1024;  // [1024][1024]

    cast_x_kernel<<<(int)(nx / 4 + 255) / 256, 256, 0, stream>>>(x, xb, (int)(nx / 4));
    tcast_all<<<dim3(16, 64), 256, 0, stream>>>(Wq, Wk, Wv, Wp, wf, wpt);
    qkv_gemm<<<768, 512, 0, stream>>>(xb, wf, bq, bk, bv, qb, kb, vtb);
    attn_kernel<<<dim3(64, 8), 256, 0, stream>>>(qb, kb, vtb, atb);
    proj_gemm<<<256, 512, 0, stream>>>(atb, wpt, bp, out);
}

// Round 9
// 255.052 us; speedup vs baseline: 1.0893x; 1.0414x over previous
//
#include <hip/hip_runtime.h>
#include <math.h>

#define B_ 4
#define T_ 2048
#define E_ 1024
#define H_ 16
#define D_ 64

typedef __bf16 bf16_t;
typedef bf16_t bf16x8 __attribute__((ext_vector_type(8)));
typedef float  f32x4  __attribute__((ext_vector_type(4)));
typedef float  f32x16 __attribute__((ext_vector_type(16)));
typedef unsigned short u16x4 __attribute__((ext_vector_type(4)));
typedef unsigned int   u32x4 __attribute__((ext_vector_type(4)));

static __device__ __forceinline__ unsigned short f2bf(float f) {
    bf16_t h = (bf16_t)f;
    return __builtin_bit_cast(unsigned short, h);
}
static __device__ __forceinline__ unsigned int pk2(float a, float b) {
    return (unsigned int)f2bf(a) | ((unsigned int)f2bf(b) << 16);
}
// native 2^x (q is pre-scaled by 0.125*log2e so this computes e^(orig S))
static __device__ __forceinline__ float ex2(float x) {
    float r; asm("v_exp_f32 %0, %1" : "=v"(r) : "v"(x)); return r;
}
// v_permlane32_swap_b32: a' = {a.row0, b.row0}, b' = {a.row1, b.row1}
static __device__ __forceinline__ void pl32swap(unsigned int& a, unsigned int& b) {
    asm("v_permlane32_swap_b32 %0, %1" : "+v"(a), "+v"(b));
}

// async global->LDS, 16B per lane; lds base wave-uniform + lane*16
#define GLD(gp, lp) __builtin_amdgcn_global_load_lds( \
    (const __attribute__((address_space(1))) unsigned int*)(gp), \
    (__attribute__((address_space(3))) unsigned int*)(lp), 16, 0, 0)

#define BAR() __builtin_amdgcn_s_barrier()
#define WAIT_LGKM0() asm volatile("s_waitcnt lgkmcnt(0)" ::: "memory")
#define VMC(n) asm volatile("s_waitcnt vmcnt(" #n ")" ::: "memory")

// ---------------------------------------------------------------------------
// x fp32 -> bf16
// ---------------------------------------------------------------------------
__global__ void cast_x_kernel(const float* __restrict__ in, unsigned short* __restrict__ out, int n4) {
    int i = blockIdx.x * blockDim.x + threadIdx.x;
    if (i >= n4) return;
    float4 v = ((const float4*)in)[i];
    ushort4 o;
    o.x = f2bf(v.x); o.y = f2bf(v.y); o.z = f2bf(v.z); o.w = f2bf(v.w);
    ((ushort4*)out)[i] = o;
}

// ---------------------------------------------------------------------------
// fused transpose-cast for all 4 weights. grid (16, 64), block 256.
// grp 0..2: Wq/Wk/Wv [h][e][d] -> wf[(grp*1024+h*64+d)][e]; grp 3: Wp [e][n] -> wpt[n][e]
// ---------------------------------------------------------------------------
__global__ void tcast_all(const float* __restrict__ Wq, const float* __restrict__ Wk,
                          const float* __restrict__ Wv, const float* __restrict__ Wp,
                          unsigned short* __restrict__ wf, unsigned short* __restrict__ wpt) {
    __shared__ unsigned short Ts[64 * 66];
    const int grp = blockIdx.y >> 4, yy = blockIdx.y & 15;
    const float* in; unsigned short* out; int yA, S;
    if (grp == 3) { in = Wp; out = wpt; yA = 64;    S = 1024; }
    else {
        in = (grp == 0) ? Wq : (grp == 1) ? Wk : Wv;
        out = wf + (size_t)grp * 1024 * 1024; yA = 65536; S = 64;
    }
    const int tid = threadIdx.x;
    const int r = tid >> 2, c4 = tid & 3;
    const float* ip = in + (size_t)yA * yy + (size_t)(blockIdx.x * 64 + r) * S + c4 * 16;
    #pragma unroll
    for (int j = 0; j < 4; ++j) {
        float4 v = *(const float4*)&ip[j * 4];
        Ts[(c4 * 16 + j * 4 + 0) * 66 + r] = f2bf(v.x);
        Ts[(c4 * 16 + j * 4 + 1) * 66 + r] = f2bf(v.y);
        Ts[(c4 * 16 + j * 4 + 2) * 66 + r] = f2bf(v.z);
        Ts[(c4 * 16 + j * 4 + 3) * 66 + r] = f2bf(v.w);
    }
    __syncthreads();
    unsigned short* op = out + (size_t)(yy * 64 + r) * 1024 + blockIdx.x * 64 + c4 * 16;
    #pragma unroll
    for (int j = 0; j < 4; ++j) {
        u16x4 pk;
        #pragma unroll
        for (int m = 0; m < 4; ++m) pk[m] = Ts[r * 66 + c4 * 16 + j * 4 + m];
        *(u16x4*)&op[j * 4] = pk;
    }
}

// ---------------------------------------------------------------------------
// 128x256-tile 8-wave GEMM core (qkv + proj): 512 thr (2Mx4N waves, 64x64
// per wave, acc[4][4]), BK=64, 2 phases/K-tile, 2 K-tiles/iteration.
// LDS 96KB: per buffer A[128][64] @0, B[256][64] @8192 (u16). 1 block/CU.
// T2 swizzle: linear GLD dest + inverse-swizzled global source (rule 21).
// STAGING LEDGER (verified r8):
//   P1: Bh(t1) | P2: A(t0+2), Bl(t0+2) | P3: Bh(t0+2) | P4: A(t1+2), Bl(t1+2)
// vmcnt(6) each phase end; tail vmcnt(2)/vmcnt(0).
// GRID MAP (r9 fix): m on the FAST axis -> default round-robin XCD
// assignment gives each XCD 8 stride-8 m-tiles of ONE n-panel
// (2MB A + 0.5MB B, L2-resident). r8's hand-swizzle was n-panel-major per
// XCD -> each XCD streamed the whole A matrix (FETCH 41->104MB regression).
// ---------------------------------------------------------------------------

#define GEMM_CORE_DECLS \
    const int tid = threadIdx.x; \
    const int w = tid >> 6, lane = tid & 63; \
    const int wr = w >> 2, wc = w & 3; \
    const int l15 = lane & 15, quad = lane >> 4, lsw = l15 & 7; \
    const int rowg = lane >> 3; \
    const int swz = ((lane & 7) ^ rowg) * 8; \
    f32x4 acc[4][4]; \
    _Pragma("unroll") for (int i_ = 0; i_ < 4; ++i_) \
        _Pragma("unroll") for (int j_ = 0; j_ < 4; ++j_) \
            acc[i_][j_] = (f32x4){0.f, 0.f, 0.f, 0.f};

#define MFMA_P(nb) \
    __builtin_amdgcn_s_setprio(1); \
    _Pragma("unroll") for (int m_ = 0; m_ < 4; ++m_) \
        _Pragma("unroll") for (int j_ = 0; j_ < 2; ++j_) \
            _Pragma("unroll") for (int k_ = 0; k_ < 2; ++k_) \
                acc[m_][(nb) + j_] = __builtin_amdgcn_mfma_f32_16x16x32_bf16( \
                    fA[m_][k_], fB[(nb) + j_][k_], acc[m_][(nb) + j_], 0, 0, 0); \
    __builtin_amdgcn_s_setprio(0);

// 8 iterations (16 K-tiles), stageA/stageB/rdA/rdB provided as lambdas
#define GEMM_K_LOOP \
    stageA(0, 0); stageA(0, 1); stageB(0, 0, 0); stageB(0, 0, 1); \
    stageB(0, 1, 0); stageB(0, 1, 1); \
    stageA(1, 0); stageA(1, 1); stageB(1, 0, 0); stageB(1, 0, 1); \
    VMC(6); BAR(); \
    _Pragma("unroll 1") \
    for (int it = 0; it < 8; ++it) { \
        const int t0 = 2 * it, t1 = 2 * it + 1; \
        const bool more = it < 7; \
        bf16x8 fA[4][2], fB[4][2]; \
        /* P1: reads fA(t0)+fBlo(t0); stage Bh(t1) */ \
        _Pragma("unroll") for (int m_ = 0; m_ < 4; ++m_) { fA[m_][0] = rdA(t0, m_, 0); fA[m_][1] = rdA(t0, m_, 1); } \
        _Pragma("unroll") for (int n_ = 0; n_ < 2; ++n_) { fB[n_][0] = rdB(t0, n_, 0); fB[n_][1] = rdB(t0, n_, 1); } \
        stageB(t1, 1, 0); stageB(t1, 1, 1); \
        BAR(); WAIT_LGKM0(); \
        MFMA_P(0); \
        VMC(6); BAR(); \
        /* P2: reads fBhi(t0); stage A(t0+2), Bl(t0+2) */ \
        _Pragma("unroll") for (int n_ = 0; n_ < 2; ++n_) { fB[2 + n_][0] = rdB(t0, 2 + n_, 0); fB[2 + n_][1] = rdB(t0, 2 + n_, 1); } \
        if (more) { stageA(t0 + 2, 0); stageA(t0 + 2, 1); stageB(t0 + 2, 0, 0); stageB(t0 + 2, 0, 1); } \
        BAR(); WAIT_LGKM0(); \
        MFMA_P(2); \
        if (more) { VMC(6); } else { VMC(2); } \
        BAR(); \
        /* P3: reads fA(t1)+fBlo(t1); stage Bh(t0+2) */ \
        _Pragma("unroll") for (int m_ = 0; m_ < 4; ++m_) { fA[m_][0] = rdA(t1, m_, 0); fA[m_][1] = rdA(t1, m_, 1); } \
        _Pragma("unroll") for (int n_ = 0; n_ < 2; ++n_) { fB[n_][0] = rdB(t1, n_, 0); fB[n_][1] = rdB(t1, n_, 1); } \
        if (more) { stageB(t0 + 2, 1, 0); stageB(t0 + 2, 1, 1); } \
        BAR(); WAIT_LGKM0(); \
        MFMA_P(0); \
        if (more) { VMC(6); } else { VMC(0); } \
        BAR(); \
        /* P4: reads fBhi(t1); stage A(t1+2), Bl(t1+2) */ \
        _Pragma("unroll") for (int n_ = 0; n_ < 2; ++n_) { fB[2 + n_][0] = rdB(t1, 2 + n_, 0); fB[2 + n_][1] = rdB(t1, 2 + n_, 1); } \
        if (more) { stageA(t1 + 2, 0); stageA(t1 + 2, 1); stageB(t1 + 2, 0, 0); stageB(t1 + 2, 0, 1); } \
        BAR(); WAIT_LGKM0(); \
        MFMA_P(2); \
        if (more) { VMC(6); } \
        BAR(); \
    }

// ---------------------------------------------------------------------------
// Fused QKV GEMM: [8192 x 1024] x [3072 x 1024]^T, 128x256 tiles.
// q scaled 0.125*log2e (+bias); k +bias; v (+bias) transposed [bh][64][T].
// grid 768 (1D, m fast), block 512.
// ---------------------------------------------------------------------------
__global__ __launch_bounds__(512, 2) void qkv_gemm(
    const unsigned short* __restrict__ xb,
    const unsigned short* __restrict__ wf,
    const float* __restrict__ bq, const float* __restrict__ bk, const float* __restrict__ bv,
    unsigned short* __restrict__ qo, unsigned short* __restrict__ ko,
    unsigned short* __restrict__ vt)
{
    __shared__ __align__(16) unsigned short sm[49152];   // 96 KiB

    // m on fast axis: XCD = bid%8 gets m-tiles {x, x+8, ...} of one n-panel
    const int bid = blockIdx.x;
    const int m0 = (bid & 63) * 128;
    const int n0 = (bid >> 6) * 256;

    GEMM_CORE_DECLS

    auto stageA = [&](int t, int g) {
        const int rb = w * 16 + g * 8;
        unsigned short* dst = sm + (t & 1) * 24576 + rb * 64;
        GLD(xb + (size_t)(m0 + rb + rowg) * 1024 + t * 64 + swz, dst);
    };
    auto stageB = [&](int t, int R, int g) {
        const int rb = w * 16 + g * 8;
        const int ar0 = (rb >> 5) * 64 + R * 32 + (rb & 31);
        unsigned short* dst = sm + (t & 1) * 24576 + 8192 + ar0 * 64;
        GLD(wf + (size_t)(n0 + ar0 + rowg) * 1024 + t * 64 + swz, dst);
    };
    auto rdA = [&](int t, int fm, int ks) {
        const int row = wr * 64 + fm * 16 + l15;
        return *(const bf16x8*)&sm[(t & 1) * 24576 + row * 64 + (((ks * 4 + quad) ^ lsw) * 8)];
    };
    auto rdB = [&](int t, int fn, int ks) {
        const int row = wc * 64 + fn * 16 + l15;
        return *(const bf16x8*)&sm[(t & 1) * 24576 + 8192 + row * 64 + (((ks * 4 + quad) ^ lsw) * 8)];
    };

    GEMM_K_LOOP

    const int which = n0 >> 10;           // q / k / v
    const int nb = n0 & 1023;
    if (which < 2) {
        const float* bias = which ? bk : bq;
        unsigned short* outp = which ? ko : qo;
        // q: fold softmax scale AND log2e for native v_exp_f32 (2^x) in attn
        const float sc = which ? 1.f : 0.125f * 1.44269504088896f;
        #pragma unroll
        for (int fm = 0; fm < 4; ++fm)
            #pragma unroll
            for (int fn = 0; fn < 4; ++fn) {
                int colg = nb + wc * 64 + fn * 16 + l15;
                int h = colg >> 6, d = colg & 63;
                float bi = bias[colg];
                #pragma unroll
                for (int r = 0; r < 4; ++r) {
                    int row = m0 + wr * 64 + fm * 16 + quad * 4 + r;
                    int b = row >> 11, t = row & 2047;
                    outp[(((size_t)b * 16 + h) * 2048 + t) * 64 + d] = f2bf((acc[fm][fn][r] + bi) * sc);
                }
            }
    } else {
        // V: transpose via LDS, 2 sub-blocks of 128(n) x 128(m), stride 136
        const int b = m0 >> 11, t0r = m0 & 2047;
        for (int nh = 0; nh < 2; ++nh) {
            __syncthreads();
            if ((wc >> 1) == nh) {
                const int cc = wc & 1;
                #pragma unroll
                for (int fm = 0; fm < 4; ++fm)
                    #pragma unroll
                    for (int fn = 0; fn < 4; ++fn) {
                        int colL = cc * 64 + fn * 16 + l15;          // 0..127
                        int colg = nb + nh * 128 + colL;
                        float bi = bv[colg];
                        u16x4 pk;
                        #pragma unroll
                        for (int r = 0; r < 4; ++r) pk[r] = f2bf(acc[fm][fn][r] + bi);
                        *(u16x4*)&sm[colL * 136 + wr * 64 + fm * 16 + quad * 4] = pk;
                    }
            }
            __syncthreads();
            const int nl = tid >> 2, tq = tid & 3;                   // col 0..127
            const int colg = nb + nh * 128 + nl;
            const int h = colg >> 6, d = colg & 63;
            unsigned short* dst = vt + (((size_t)b * 16 + h) * 64 + d) * 2048 + t0r + tq * 32;
            #pragma unroll
            for (int j = 0; j < 4; ++j)
                *(float4*)&dst[j * 8] = *(const float4*)&sm[nl * 136 + tq * 32 + j * 8];
        }
    }
}

// ---------------------------------------------------------------------------
// Output projection: A = att2 bf16 [b*16+h][t][64] (gathered), B = Wp^T,
// fp32 out + bias. 128x256 tiles, same core. grid 256 (1D, m fast), block 512.
// ---------------------------------------------------------------------------
__global__ __launch_bounds__(512, 2) void proj_gemm(
    const unsigned short* __restrict__ A,
    const unsigned short* __restrict__ wpt,
    const float* __restrict__ bp,
    float* __restrict__ out)
{
    __shared__ __align__(16) unsigned short sm[49152];   // 96 KiB

    const int bid = blockIdx.x;
    const int m0 = (bid & 63) * 128;
    const int n0 = (bid >> 6) * 256;

    GEMM_CORE_DECLS

    // A element (m,k) at A[((m>>11)*16 + (k>>6))*131072 + (m&2047)*64 + (k&63)]
    const unsigned short* Ab = A + (size_t)(m0 >> 11) * 16 * 131072 + (size_t)(m0 & 2047) * 64;
    auto stageA = [&](int t, int g) {
        const int rb = w * 16 + g * 8;
        unsigned short* dst = sm + (t & 1) * 24576 + rb * 64;
        GLD(Ab + (size_t)t * 131072 + (rb + rowg) * 64 + swz, dst);
    };
    auto stageB = [&](int t, int R, int g) {
        const int rb = w * 16 + g * 8;
        const int ar0 = (rb >> 5) * 64 + R * 32 + (rb & 31);
        unsigned short* dst = sm + (t & 1) * 24576 + 8192 + ar0 * 64;
        GLD(wpt + (size_t)(n0 + ar0 + rowg) * 1024 + t * 64 + swz, dst);
    };
    auto rdA = [&](int t, int fm, int ks) {
        const int row = wr * 64 + fm * 16 + l15;
        return *(const bf16x8*)&sm[(t & 1) * 24576 + row * 64 + (((ks * 4 + quad) ^ lsw) * 8)];
    };
    auto rdB = [&](int t, int fn, int ks) {
        const int row = wc * 64 + fn * 16 + l15;
        return *(const bf16x8*)&sm[(t & 1) * 24576 + 8192 + row * 64 + (((ks * 4 + quad) ^ lsw) * 8)];
    };

    GEMM_K_LOOP

    #pragma unroll
    for (int fm = 0; fm < 4; ++fm)
        #pragma unroll
        for (int fn = 0; fn < 4; ++fn) {
            int col = n0 + wc * 64 + fn * 16 + l15;
            float bi = bp[col];
            #pragma unroll
            for (int r = 0; r < 4; ++r) {
                int row = m0 + wr * 64 + fm * 16 + quad * 4 + r;
                out[(size_t)row * 1024 + col] = acc[fm][fn][r] + bi;
            }
        }
}

// ---------------------------------------------------------------------------
// Flash attention v4 (unchanged): 128 q/block, KVBLK=128, GLD double-buffered
// staging, in-register P via v_permlane32_swap, native v_exp_f32 (q
// pre-scaled 0.125*log2e). grid (64 bh, 8 pairs), block 256, LDS 64KB.
// C/D layout (verified): col=lane&31, row=(reg&3)+8*(reg>>2)+4*(lane>>5).
// ---------------------------------------------------------------------------
__global__ __launch_bounds__(256, 2) void attn_kernel(
    const unsigned short* __restrict__ q, const unsigned short* __restrict__ k,
    const unsigned short* __restrict__ vt, unsigned short* __restrict__ att2)
{
    __shared__ __align__(16) unsigned short KV[2][2][8192];   // [buf][K|V]

    const int tid = threadIdx.x;
    const int w = tid >> 6, lane = tid & 63;
    const int l31 = lane & 31, h = lane >> 5;
    const int bh = blockIdx.x;
    const int rs = l31 & 7, rv = l31 & 15;

    const unsigned short* kb = k  + (size_t)bh * 2048 * 64;
    const unsigned short* vb = vt + (size_t)bh * 64 * 2048;

    // K staging: wave w rows 32w+8r+(lane>>3), slot lane&7 <- chunk (lane&7)^(row&7)
    const size_t kOff = (size_t)(32 * w + (lane >> 3)) * 64 + (size_t)(((lane & 7) ^ (lane >> 3)) * 8);
    // V staging: wave w d-rows 16w+4r+(lane>>4), slot lane&15 <- chunk slot^(d&15)
    const int vRow = lane >> 4, vc = lane & 15;
    size_t vOff[4];
    #pragma unroll
    for (int r = 0; r < 4; ++r)
        vOff[r] = (size_t)(16 * w + 4 * r + vRow) * 2048
                + (size_t)((vc ^ ((4 * r + vRow) & 15)) * 8);

    auto stage = [&](int jt, int buf) {
        unsigned short* dK = &KV[buf][0][w * 2048];
        unsigned short* dV = &KV[buf][1][w * 2048];
        const unsigned short* sK = kb + kOff + (size_t)jt * 8192;
        #pragma unroll
        for (int r = 0; r < 4; ++r) GLD(sK + r * 512, dK + r * 512);
        #pragma unroll
        for (int r = 0; r < 4; ++r) GLD(vb + vOff[r] + jt * 128, dV + r * 512);
    };

    for (int leg = 0; leg < 2; ++leg) {
        const int qtile = leg ? (15 - (int)blockIdx.y) : (int)blockIdx.y;
        const int qb0 = qtile * 128;
        const int qmin = qb0 + w * 32, qmax = qmin + 31;
        const int qg = qmin + l31;             // query owned as S^T COLUMN
        const int trips = qtile + 1;           // 128-key tiles

        // Q B-fragments straight from global: B[k=d][n=query]
        bf16x8 fQ[4];
        {
            const unsigned short* qp = q + ((size_t)bh * 2048 + qg) * 64 + h * 8;
            #pragma unroll
            for (int ks = 0; ks < 4; ++ks) fQ[ks] = *(const bf16x8*)&qp[ks * 16];
        }

        f32x16 Oa[2], Ob[2];
        #pragma unroll
        for (int nt = 0; nt < 2; ++nt)
            #pragma unroll
            for (int i = 0; i < 16; ++i) { Oa[nt][i] = 0.f; Ob[nt][i] = 0.f; }
        float lsum = 0.f;

        stage(0, 0);
        VMC(0);
        BAR();

        for (int jt = 0; jt < trips; ++jt) {
            const int buf = jt & 1;
            if (jt + 1 < trips) stage(jt + 1, buf ^ 1);
            const unsigned short* Ks = KV[buf][0];
            const unsigned short* Vs = KV[buf][1];
            const int key0 = jt * 128;

            // QK^T: 4 independent 32-key subtile chains
            f32x16 S[4];
            #pragma unroll
            for (int kt = 0; kt < 4; ++kt)
                #pragma unroll
                for (int i = 0; i < 16; ++i) S[kt][i] = 0.f;
            __builtin_amdgcn_s_setprio(1);
            #pragma unroll
            for (int kt = 0; kt < 4; ++kt) {
                if (key0 + 32 * kt <= qmax) {
                    const int row = kt * 32 + l31;
                    #pragma unroll
                    for (int ks = 0; ks < 4; ++ks) {
                        bf16x8 aK = *(const bf16x8*)&Ks[row * 64 + (((2 * ks + h) ^ rs) * 8)];
                        S[kt] = __builtin_amdgcn_mfma_f32_32x32x16_bf16(aK, fQ[ks], S[kt], 0, 0, 0);
                    }
                }
            }
            __builtin_amdgcn_s_setprio(0);

            // per subtile: softmax (native 2^x) -> in-reg P (permlane swap) -> PV
            #pragma unroll
            for (int kt = 0; kt < 4; ++kt) {
                if (key0 + 32 * kt <= qmax) {
                    const bool nm = (key0 + 32 * kt + 31) > qmin;
                    unsigned int e0[4], e1[4];
                    float lst = 0.f;
                    #pragma unroll
                    for (int g = 0; g < 4; ++g) {
                        float p[4];
                        #pragma unroll
                        for (int r = 0; r < 4; ++r) {
                            float pv = ex2(S[kt][4 * g + r]);
                            if (nm) {
                                int key = key0 + kt * 32 + 8 * g + 4 * h + r;
                                if (key > qg) pv = 0.f;
                            }
                            p[r] = pv;
                        }
                        lst += (p[0] + p[1]) + (p[2] + p[3]);
                        e0[g] = pk2(p[0], p[1]);
                        e1[g] = pk2(p[2], p[3]);
                    }
                    lsum += lst;

                    __builtin_amdgcn_s_setprio(1);
                    #pragma unroll
                    for (int s = 0; s < 2; ++s) {
                        unsigned int a = e0[2 * s], b = e0[2 * s + 1];
                        pl32swap(a, b);                       // a={keys+0,+1}, b={+4,+5}
                        unsigned int c2 = e1[2 * s], d2 = e1[2 * s + 1];
                        pl32swap(c2, d2);                     // c2={+2,+3}, d2={+6,+7}
                        u32x4 t; t[0] = a; t[1] = c2; t[2] = b; t[3] = d2;
                        bf16x8 aP = __builtin_bit_cast(bf16x8, t);
                        const int cb = 4 * kt + 2 * s;        // V chunk c = cb + h
                        #pragma unroll
                        for (int nt = 0; nt < 2; ++nt) {
                            const int drow = nt * 32 + l31;
                            bf16x8 bV = *(const bf16x8*)&Vs[drow * 128 + (((cb + h) ^ rv) * 8)];
                            if (kt & 1)
                                Ob[nt] = __builtin_amdgcn_mfma_f32_32x32x16_bf16(aP, bV, Ob[nt], 0, 0, 0);
                            else
                                Oa[nt] = __builtin_amdgcn_mfma_f32_32x32x16_bf16(aP, bV, Oa[nt], 0, 0, 0);
                        }
                    }
                    __builtin_amdgcn_s_setprio(0);
                }
            }

            VMC(0);   // next tile landed
            BAR();
        }

        // lsum split across half-waves (query qg in lanes l31 and l31+32)
        lsum += __shfl_xor(lsum, 32);
        const float inv = 1.f / lsum;

        // O[nt][4g+r]: query row 8g+4h+r, d col nt*32+l31 (C/D layout)
        unsigned short* ob = att2 + ((size_t)bh * 2048 + qmin) * 64;
        #pragma unroll
        for (int g = 0; g < 4; ++g)
            #pragma unroll
            for (int r = 0; r < 4; ++r) {
                const int qy = 8 * g + 4 * h + r;
                const float iv = __shfl(inv, qy);
                #pragma unroll
                for (int nt = 0; nt < 2; ++nt)
                    ob[(size_t)qy * 64 + nt * 32 + l31] =
                        f2bf((Oa[nt][4 * g + r] + Ob[nt][4 * g + r]) * iv);
            }
    }
}

extern "C" void kernel_launch(void* const* d_in, const int* in_sizes, int n_in,
                              void* d_out, int out_size, void* d_ws, size_t ws_size,
                              hipStream_t stream) {
    const float* x  = (const float*)d_in[0];
    const float* Wq = (const float*)d_in[1];
    const float* Wk = (const float*)d_in[2];
    const float* Wv = (const float*)d_in[3];
    const float* bq = (const float*)d_in[4];
    const float* bk = (const float*)d_in[5];
    const float* bv = (const float*)d_in[6];
    const float* Wp = (const float*)d_in[7];
    const float* bp = (const float*)d_in[8];
    float* out = (float*)d_out;

    const size_t nx = (size_t)B_ * T_ * E_;
    unsigned short* base = (unsigned short*)d_ws;
    unsigned short* xb  = base;
    unsigned short* qb  = xb + nx;
    unsigned short* kb  = qb + nx;
    unsigned short* vtb = kb + nx;
    unsigned short* atb = vtb + nx;          // [bh][t][64]
    unsigned short* wf  = atb + nx;          // [3072][1024]
    unsigned short* wpt = wf + 3072 * 1024;  // [1024][1024]

    cast_x_kernel<<<(int)(nx / 4 + 255) / 256, 256, 0, stream>>>(x, xb, (int)(nx / 4));
    tcast_all<<<dim3(16, 64), 256, 0, stream>>>(Wq, Wk, Wv, Wp, wf, wpt);
    qkv_gemm<<<768, 512, 0, stream>>>(xb, wf, bq, bk, bv, qb, kb, vtb);
    attn_kernel<<<dim3(64, 8), 256, 0, stream>>>(qb, kb, vtb, atb);
    proj_gemm<<<256, 512, 0, stream>>>(atb, wpt, bp, out);
}